// Round 3
// baseline (14389.424 us; speedup 1.0000x reference)
//
#include <hip/hip_runtime.h>
#include <hip/hip_bf16.h>

typedef __hip_bfloat16 bf16;

// Problem constants
#define NB 32      // batch
#define NSEQ 540   // sequence length
#define ND 512     // model dim
#define NH 8       // heads
#define NDH 64     // head dim
#define NHB 256    // NH*NB
#define NM 17280   // NB*NSEQ
#define NPOS 1079  // 2*539+1

// bf16x8 -> 8 floats (16B load)
__device__ __forceinline__ void load8(const bf16* __restrict__ p, float* f) {
  const uint4 u = *reinterpret_cast<const uint4*>(p);
  f[0] = __uint_as_float(u.x << 16);
  f[1] = __uint_as_float(u.x & 0xffff0000u);
  f[2] = __uint_as_float(u.y << 16);
  f[3] = __uint_as_float(u.y & 0xffff0000u);
  f[4] = __uint_as_float(u.z << 16);
  f[5] = __uint_as_float(u.z & 0xffff0000u);
  f[6] = __uint_as_float(u.w << 16);
  f[7] = __uint_as_float(u.w & 0xffff0000u);
}

// fp32x8 -> 8 floats (two 16B loads)
__device__ __forceinline__ void load8f(const float* __restrict__ p, float* f) {
  const float4 a = *reinterpret_cast<const float4*>(p);
  const float4 b = *reinterpret_cast<const float4*>(p + 4);
  f[0] = a.x; f[1] = a.y; f[2] = a.z; f[3] = a.w;
  f[4] = b.x; f[5] = b.y; f[6] = b.z; f[7] = b.w;
}

// ---------------------------------------------------------------------------
// K1: QKV projection.  X[17280,512] @ W[512,512] + b  -> head-major [H*B,N,DH]
// fp32 in, bf16 out. 64x64 tile, BK=32, 256 threads, 4x4 per thread.
// ---------------------------------------------------------------------------
__global__ __launch_bounds__(256) void qkv_proj(
    const float* __restrict__ X,
    const float* __restrict__ Wq, const float* __restrict__ bq,
    const float* __restrict__ Wk, const float* __restrict__ bk,
    const float* __restrict__ Wv, const float* __restrict__ bv,
    bf16* __restrict__ qh, bf16* __restrict__ kh, bf16* __restrict__ vh) {
  __shared__ float AsT[32][68];  // [k][m], padded
  __shared__ float Bs[32][64];   // [k][n]
  const int tid = threadIdx.x;
  const int bx = blockIdx.x;   // n-tile == head (0..7)
  const int by = blockIdx.y;   // m-tile (0..269)
  const int sel = blockIdx.z;  // 0=q 1=k 2=v
  const float* W = (sel == 0) ? Wq : ((sel == 1) ? Wk : Wv);
  const float* bias = (sel == 0) ? bq : ((sel == 1) ? bk : bv);
  bf16* outp = (sel == 0) ? qh : ((sel == 1) ? kh : vh);
  const int m0 = by * 64, n0 = bx * 64;
  const int tx = tid & 15, ty = tid >> 4;
  const int arow = tid >> 2, agrp = tid & 3;  // A tile: 64 rows x 4 groups of 8
  const int brow = tid >> 3, bgrp = tid & 7;  // B tile: 32 rows x 8 groups of 8

  float acc[4][4] = {};

  for (int k0 = 0; k0 < 512; k0 += 32) {
    float af[8], bfv[8];
    load8f(X + (size_t)(m0 + arow) * 512 + k0 + agrp * 8, af);
    load8f(W + (size_t)(k0 + brow) * 512 + n0 + bgrp * 8, bfv);
    __syncthreads();  // previous compute done before overwriting LDS
#pragma unroll
    for (int i = 0; i < 8; i++) AsT[agrp * 8 + i][arow] = af[i];
    *(float4*)&Bs[brow][bgrp * 8] = make_float4(bfv[0], bfv[1], bfv[2], bfv[3]);
    *(float4*)&Bs[brow][bgrp * 8 + 4] = make_float4(bfv[4], bfv[5], bfv[6], bfv[7]);
    __syncthreads();
#pragma unroll
    for (int kk = 0; kk < 32; kk++) {
      const float4 a = *(const float4*)&AsT[kk][ty * 4];
      const float4 b = *(const float4*)&Bs[kk][tx * 4];
      acc[0][0] += a.x * b.x; acc[0][1] += a.x * b.y; acc[0][2] += a.x * b.z; acc[0][3] += a.x * b.w;
      acc[1][0] += a.y * b.x; acc[1][1] += a.y * b.y; acc[1][2] += a.y * b.z; acc[1][3] += a.y * b.w;
      acc[2][0] += a.z * b.x; acc[2][1] += a.z * b.y; acc[2][2] += a.z * b.z; acc[2][3] += a.z * b.w;
      acc[3][0] += a.w * b.x; acc[3][1] += a.w * b.y; acc[3][2] += a.w * b.z; acc[3][3] += a.w * b.w;
    }
  }

  // epilogue: + bias, remap to head-major [h*NB + b, seq, dh]
  const int h = bx;  // n0 = h*64
#pragma unroll
  for (int i = 0; i < 4; i++) {
    const int m = m0 + ty * 4 + i;
    const int bidx = m / NSEQ;
    const int seq = m - bidx * NSEQ;
    const size_t base = (((size_t)(h * NB + bidx)) * NSEQ + seq) * NDH + tx * 4;
#pragma unroll
    for (int j = 0; j < 4; j++) {
      const float v = acc[i][j] + bias[n0 + tx * 4 + j];
      outp[base + j] = __float2bfloat16(v);
    }
  }
}

// ---------------------------------------------------------------------------
// K2: attention. Block = (q-tile of 16, head-batch x). 256 threads.
// Scores = q . (k + pos_k[k - q + 539]), scaled 1/8, key-masked softmax, PV.
// q/k/v bf16, pos fp32, ctx fp32.
// ---------------------------------------------------------------------------
__global__ __launch_bounds__(256) void attn(
    const bf16* __restrict__ qh, const bf16* __restrict__ kh,
    const bf16* __restrict__ vh, const float* __restrict__ pos,
    const int* __restrict__ vlen, float* __restrict__ ctx) {
  __shared__ float Qs[16][68];
  __shared__ float Ks[64][68];   // reused for V in phase C
  __shared__ float Ps[79][68];
  __shared__ float S[16][545];
  __shared__ float red[16][17];

  const int tid = threadIdx.x;
  const int qb = blockIdx.x;  // 0..33
  const int x = blockIdx.y;   // 0..255  (x = h*NB + b)
  const int b = x & 31, h = x >> 5;
  const int q0 = qb * 16;
  const int valid = vlen[b];
  const bf16* qbase = qh + (size_t)x * NSEQ * NDH;
  const bf16* kbase = kh + (size_t)x * NSEQ * NDH;
  const bf16* vbase = vh + (size_t)x * NSEQ * NDH;

  // load Q tile (zero-fill rows past NSEQ)
  if (tid < 128) {
    const int row = tid >> 3, grp = tid & 7;
    const int q = q0 + row;
    float f[8];
    if (q < NSEQ) {
      load8(qbase + (size_t)q * NDH + grp * 8, f);
    } else {
#pragma unroll
      for (int i = 0; i < 8; i++) f[i] = 0.f;
    }
    *(float4*)&Qs[row][grp * 8] = make_float4(f[0], f[1], f[2], f[3]);
    *(float4*)&Qs[row][grp * 8 + 4] = make_float4(f[4], f[5], f[6], f[7]);
  }

  const int qq0 = (tid >> 5) * 2;   // 0..14
  const int kk0 = (tid & 31) * 2;   // 0..62
  const int pbase = kk0 - qq0 + 15; // 1..77

  // -------- phase A: scores --------
  for (int k0 = 0; k0 < NSEQ; k0 += 64) {
    const int ntile = min(64, NSEQ - k0);
    __syncthreads();  // previous compute done (also publishes Qs on iter 0)
    for (int u = tid; u < 512; u += 256) {
      const int row = u >> 3, grp = u & 7;
      const int kk = min(k0 + row, NSEQ - 1);
      float f[8];
      load8(kbase + (size_t)kk * NDH + grp * 8, f);
      *(float4*)&Ks[row][grp * 8] = make_float4(f[0], f[1], f[2], f[3]);
      *(float4*)&Ks[row][grp * 8 + 4] = make_float4(f[4], f[5], f[6], f[7]);
    }
    const int relmin = k0 - q0 + 524;  // (k0) - (q0+15) + 539
    for (int u = tid; u < 632; u += 256) {
      const int row = u >> 3, grp = u & 7;
      int g = relmin + row;
      g = max(0, min(NPOS - 1, g));  // clamped rows are never consumed
      float f[8];
      load8f(pos + (size_t)g * NDH + grp * 8, f);
      *(float4*)&Ps[row][grp * 8] = make_float4(f[0], f[1], f[2], f[3]);
      *(float4*)&Ps[row][grp * 8 + 4] = make_float4(f[4], f[5], f[6], f[7]);
    }
    __syncthreads();

    float a00 = 0.f, a01 = 0.f, a10 = 0.f, a11 = 0.f;
#pragma unroll
    for (int d = 0; d < 64; d += 4) {
      const float4 qa = *(const float4*)&Qs[qq0][d];
      const float4 qc = *(const float4*)&Qs[qq0 + 1][d];
      const float4 ka = *(const float4*)&Ks[kk0][d];
      const float4 kc = *(const float4*)&Ks[kk0 + 1][d];
      const float4 pm = *(const float4*)&Ps[pbase - 1][d];
      const float4 p0 = *(const float4*)&Ps[pbase][d];
      const float4 pp = *(const float4*)&Ps[pbase + 1][d];
      a00 += qa.x * (ka.x + p0.x) + qa.y * (ka.y + p0.y) + qa.z * (ka.z + p0.z) + qa.w * (ka.w + p0.w);
      a01 += qa.x * (kc.x + pp.x) + qa.y * (kc.y + pp.y) + qa.z * (kc.z + pp.z) + qa.w * (kc.w + pp.w);
      a10 += qc.x * (ka.x + pm.x) + qc.y * (ka.y + pm.y) + qc.z * (ka.z + pm.z) + qc.w * (ka.w + pm.w);
      a11 += qc.x * (kc.x + p0.x) + qc.y * (kc.y + p0.y) + qc.z * (kc.z + p0.z) + qc.w * (kc.w + p0.w);
    }
    if (kk0 < ntile) {
      S[qq0][k0 + kk0] = a00 * 0.125f;
      S[qq0 + 1][k0 + kk0] = a10 * 0.125f;
    }
    if (kk0 + 1 < ntile) {
      S[qq0][k0 + kk0 + 1] = a01 * 0.125f;
      S[qq0 + 1][k0 + kk0 + 1] = a11 * 0.125f;
    }
  }
  __syncthreads();

  // -------- phase B: masked softmax over k < valid --------
  const int r = tid >> 4, c = tid & 15;
  float ml = -1e30f;
  for (int k = c; k < valid; k += 16) ml = fmaxf(ml, S[r][k]);
  red[r][c] = ml;
  __syncthreads();
  if (c == 0) {
    float m = red[r][0];
#pragma unroll
    for (int i = 1; i < 16; i++) m = fmaxf(m, red[r][i]);
    red[r][16] = m;
  }
  __syncthreads();
  const float rowmax = red[r][16];
  float sl = 0.f;
  for (int k = c; k < valid; k += 16) {
    const float e = __expf(S[r][k] - rowmax);
    S[r][k] = e;
    sl += e;
  }
  red[r][c] = sl;
  __syncthreads();
  if (c == 0) {
    float s = 0.f;
#pragma unroll
    for (int i = 0; i < 16; i++) s += red[r][i];
    red[r][16] = 1.f / s;
  }
  __syncthreads();
  const float inv = red[r][16];
  for (int k = c; k < NSEQ; k += 16) S[r][k] = (k < valid) ? S[r][k] * inv : 0.f;

  // -------- phase C: out = P @ V --------
  float o0 = 0.f, o1 = 0.f, o2 = 0.f, o3 = 0.f;
  const int oq = tid >> 4;
  const int dh0 = (tid & 15) * 4;
  for (int k0 = 0; k0 < NSEQ; k0 += 64) {
    const int ntile = min(64, NSEQ - k0);
    __syncthreads();  // previous compute done before overwriting Ks(=Vs)
    for (int u = tid; u < 512; u += 256) {
      const int row = u >> 3, grp = u & 7;
      const int kk = min(k0 + row, NSEQ - 1);
      float f[8];
      load8(vbase + (size_t)kk * NDH + grp * 8, f);
      *(float4*)&Ks[row][grp * 8] = make_float4(f[0], f[1], f[2], f[3]);
      *(float4*)&Ks[row][grp * 8 + 4] = make_float4(f[4], f[5], f[6], f[7]);
    }
    __syncthreads();
    for (int kk = 0; kk < ntile; kk++) {
      const float p = S[oq][k0 + kk];
      const float4 v4 = *(const float4*)&Ks[kk][dh0];
      o0 += p * v4.x;
      o1 += p * v4.y;
      o2 += p * v4.z;
      o3 += p * v4.w;
    }
  }
  const int q = q0 + oq;
  if (q < NSEQ) {
    const size_t off = ((size_t)b * NSEQ + q) * ND + h * NDH + dh0;
    *(float4*)&ctx[off] = make_float4(o0, o1, o2, o3);
  }
}

// ---------------------------------------------------------------------------
// K3: out projection + bias + residual. ctx[17280,512] @ Wh + bh + query
// all fp32.
// ---------------------------------------------------------------------------
__global__ __launch_bounds__(256) void out_proj(
    const float* __restrict__ ctx, const float* __restrict__ Wh,
    const float* __restrict__ bh, const float* __restrict__ query,
    float* __restrict__ tmp) {
  __shared__ float AsT[32][68];
  __shared__ float Bs[32][64];
  const int tid = threadIdx.x;
  const int bx = blockIdx.x;  // n-tile
  const int by = blockIdx.y;  // m-tile
  const int m0 = by * 64, n0 = bx * 64;
  const int tx = tid & 15, ty = tid >> 4;
  const int arow = tid >> 2, agrp = tid & 3;
  const int brow = tid >> 3, bgrp = tid & 7;

  float acc[4][4] = {};

  for (int k0 = 0; k0 < 512; k0 += 32) {
    float af[8], bfv[8];
    load8f(ctx + (size_t)(m0 + arow) * 512 + k0 + agrp * 8, af);
    load8f(Wh + (size_t)(k0 + brow) * 512 + n0 + bgrp * 8, bfv);
    __syncthreads();
#pragma unroll
    for (int i = 0; i < 8; i++) AsT[agrp * 8 + i][arow] = af[i];
    *(float4*)&Bs[brow][bgrp * 8] = make_float4(bfv[0], bfv[1], bfv[2], bfv[3]);
    *(float4*)&Bs[brow][bgrp * 8 + 4] = make_float4(bfv[4], bfv[5], bfv[6], bfv[7]);
    __syncthreads();
#pragma unroll
    for (int kk = 0; kk < 32; kk++) {
      const float4 a = *(const float4*)&AsT[kk][ty * 4];
      const float4 b = *(const float4*)&Bs[kk][tx * 4];
      acc[0][0] += a.x * b.x; acc[0][1] += a.x * b.y; acc[0][2] += a.x * b.z; acc[0][3] += a.x * b.w;
      acc[1][0] += a.y * b.x; acc[1][1] += a.y * b.y; acc[1][2] += a.y * b.z; acc[1][3] += a.y * b.w;
      acc[2][0] += a.z * b.x; acc[2][1] += a.z * b.y; acc[2][2] += a.z * b.z; acc[2][3] += a.z * b.w;
      acc[3][0] += a.w * b.x; acc[3][1] += a.w * b.y; acc[3][2] += a.w * b.z; acc[3][3] += a.w * b.w;
    }
  }

#pragma unroll
  for (int i = 0; i < 4; i++) {
    const int m = m0 + ty * 4 + i;
    const size_t off = (size_t)m * 512 + n0 + tx * 4;
    const float4 qv = *(const float4*)&query[off];
    float4 rv;
    rv.x = acc[i][0] + bh[n0 + tx * 4 + 0] + qv.x;
    rv.y = acc[i][1] + bh[n0 + tx * 4 + 1] + qv.y;
    rv.z = acc[i][2] + bh[n0 + tx * 4 + 2] + qv.z;
    rv.w = acc[i][3] + bh[n0 + tx * 4 + 3] + qv.w;
    *(float4*)&tmp[off] = rv;
  }
}

// ---------------------------------------------------------------------------
// K4: layernorm over D=512, eps=1e-7. One block per row, 256 threads x 2 elems.
// ---------------------------------------------------------------------------
__global__ __launch_bounds__(256) void lnorm(
    const float* __restrict__ tmp, const float* __restrict__ gamma,
    const float* __restrict__ beta, float* __restrict__ out) {
  __shared__ float sred[256];
  const int row = blockIdx.x;
  const int tid = threadIdx.x;
  const size_t base = (size_t)row * 512;
  const float x0 = tmp[base + tid];
  const float x1 = tmp[base + 256 + tid];

  sred[tid] = x0 + x1;
  __syncthreads();
  for (int o = 128; o > 0; o >>= 1) {
    if (tid < o) sred[tid] += sred[tid + o];
    __syncthreads();
  }
  const float mean = sred[0] * (1.f / 512.f);
  __syncthreads();
  const float d0 = x0 - mean, d1 = x1 - mean;
  sred[tid] = d0 * d0 + d1 * d1;
  __syncthreads();
  for (int o = 128; o > 0; o >>= 1) {
    if (tid < o) sred[tid] += sred[tid + o];
    __syncthreads();
  }
  const float var = sred[0] * (1.f / 512.f);
  const float rstd = rsqrtf(var + 1e-7f);
  out[base + tid] = d0 * rstd * gamma[tid] + beta[tid];
  out[base + 256 + tid] = d1 * rstd * gamma[tid + 256] + beta[tid + 256];
}

// ---------------------------------------------------------------------------
// Workspace: q/k/v head-major bf16 = 3 x 17.7 MB = 53.1 MB.
// ctx (fp32) lives in d_out (exactly out-sized); pre-LN tmp (fp32) reuses the
// qh+kh region (35.4 MB, dead after attn); lnorm writes final fp32 to d_out.
// ---------------------------------------------------------------------------
extern "C" void kernel_launch(void* const* d_in, const int* in_sizes, int n_in,
                              void* d_out, int out_size, void* d_ws, size_t ws_size,
                              hipStream_t stream) {
  const float* query = (const float*)d_in[0];
  const float* Wq = (const float*)d_in[1];
  const float* bq = (const float*)d_in[2];
  const float* Wk = (const float*)d_in[3];
  const float* bk = (const float*)d_in[4];
  const float* Wv = (const float*)d_in[5];
  const float* bv = (const float*)d_in[6];
  const float* Wh = (const float*)d_in[7];
  const float* bh = (const float*)d_in[8];
  const float* pos = (const float*)d_in[9];
  const float* gamma = (const float*)d_in[10];
  const float* beta = (const float*)d_in[11];
  const int* vlen = (const int*)d_in[12];

  bf16* ws = (bf16*)d_ws;
  const size_t QSZ = (size_t)NHB * NSEQ * NDH;  // 8,847,360 elems
  bf16* qh = ws;
  bf16* kh = ws + QSZ;
  bf16* vh = ws + 2 * QSZ;
  float* ctx = (float*)d_out;  // d_out doubles as ctx scratch
  float* tmp = (float*)d_ws;   // reuse qh+kh region (dead after attn), 35.4 MB
  (void)ws_size;

  qkv_proj<<<dim3(8, 270, 3), 256, 0, stream>>>(query, Wq, bq, Wk, bk, Wv, bv, qh, kh, vh);
  attn<<<dim3(34, 256), 256, 0, stream>>>(qh, kh, vh, pos, vlen, ctx);
  out_proj<<<dim3(8, 270), 256, 0, stream>>>(ctx, Wh, bh, query, tmp);
  lnorm<<<NM, 256, 0, stream>>>(tmp, gamma, beta, (float*)d_out);
}

// Round 4
// 1544.972 us; speedup vs baseline: 9.3137x; 9.3137x over previous
//
#include <hip/hip_runtime.h>
#include <hip/hip_bf16.h>

typedef __hip_bfloat16 bf16;

// Problem constants
#define NB 32      // batch
#define NSEQ 540   // sequence length
#define ND 512     // model dim
#define NH 8       // heads
#define NDH 64     // head dim
#define NHB 256    // NH*NB
#define NM 17280   // NB*NSEQ
#define NPOS 1079  // 2*539+1

// bf16x8 -> 8 floats (16B load)
__device__ __forceinline__ void load8(const bf16* __restrict__ p, float* f) {
  const uint4 u = *reinterpret_cast<const uint4*>(p);
  f[0] = __uint_as_float(u.x << 16);
  f[1] = __uint_as_float(u.x & 0xffff0000u);
  f[2] = __uint_as_float(u.y << 16);
  f[3] = __uint_as_float(u.y & 0xffff0000u);
  f[4] = __uint_as_float(u.z << 16);
  f[5] = __uint_as_float(u.z & 0xffff0000u);
  f[6] = __uint_as_float(u.w << 16);
  f[7] = __uint_as_float(u.w & 0xffff0000u);
}

// fp32x8 -> 8 floats (two 16B loads)
__device__ __forceinline__ void load8f(const float* __restrict__ p, float* f) {
  const float4 a = *reinterpret_cast<const float4*>(p);
  const float4 b = *reinterpret_cast<const float4*>(p + 4);
  f[0] = a.x; f[1] = a.y; f[2] = a.z; f[3] = a.w;
  f[4] = b.x; f[5] = b.y; f[6] = b.z; f[7] = b.w;
}

// XOR swizzle for K/V/P LDS tiles (row stride 64 floats, 16 float4-groups):
// float4 group g of row r lives at group g ^ ((r>>1)&15). Breaks the
// 8-way bank conflict of stride-2-row reads down to ~4-way.
__device__ __forceinline__ int swz(int row, int grp) {
  return (grp ^ ((row >> 1) & 15)) * 4;
}

// ---------------------------------------------------------------------------
// K1: QKV projection.  X[17280,512] @ W[512,512] + b  -> head-major [H*B,N,DH]
// fp32 in, bf16 out. 64x64 tile, BK=32, 256 threads, 4x4 per thread.
// ---------------------------------------------------------------------------
__global__ __launch_bounds__(256) void qkv_proj(
    const float* __restrict__ X,
    const float* __restrict__ Wq, const float* __restrict__ bq,
    const float* __restrict__ Wk, const float* __restrict__ bk,
    const float* __restrict__ Wv, const float* __restrict__ bv,
    bf16* __restrict__ qh, bf16* __restrict__ kh, bf16* __restrict__ vh) {
  __shared__ float AsT[32][68];  // [k][m], padded
  __shared__ float Bs[32][64];   // [k][n]
  const int tid = threadIdx.x;
  const int bx = blockIdx.x;   // n-tile == head (0..7)
  const int by = blockIdx.y;   // m-tile (0..269)
  const int sel = blockIdx.z;  // 0=q 1=k 2=v
  const float* W = (sel == 0) ? Wq : ((sel == 1) ? Wk : Wv);
  const float* bias = (sel == 0) ? bq : ((sel == 1) ? bk : bv);
  bf16* outp = (sel == 0) ? qh : ((sel == 1) ? kh : vh);
  const int m0 = by * 64, n0 = bx * 64;
  const int tx = tid & 15, ty = tid >> 4;
  const int arow = tid >> 2, agrp = tid & 3;  // A tile: 64 rows x 4 groups of 8
  const int brow = tid >> 3, bgrp = tid & 7;  // B tile: 32 rows x 8 groups of 8

  float acc[4][4] = {};

  for (int k0 = 0; k0 < 512; k0 += 32) {
    float af[8], bfv[8];
    load8f(X + (size_t)(m0 + arow) * 512 + k0 + agrp * 8, af);
    load8f(W + (size_t)(k0 + brow) * 512 + n0 + bgrp * 8, bfv);
    __syncthreads();  // previous compute done before overwriting LDS
#pragma unroll
    for (int i = 0; i < 8; i++) AsT[agrp * 8 + i][arow] = af[i];
    *(float4*)&Bs[brow][bgrp * 8] = make_float4(bfv[0], bfv[1], bfv[2], bfv[3]);
    *(float4*)&Bs[brow][bgrp * 8 + 4] = make_float4(bfv[4], bfv[5], bfv[6], bfv[7]);
    __syncthreads();
#pragma unroll
    for (int kk = 0; kk < 32; kk++) {
      const float4 a = *(const float4*)&AsT[kk][ty * 4];
      const float4 b = *(const float4*)&Bs[kk][tx * 4];
      acc[0][0] += a.x * b.x; acc[0][1] += a.x * b.y; acc[0][2] += a.x * b.z; acc[0][3] += a.x * b.w;
      acc[1][0] += a.y * b.x; acc[1][1] += a.y * b.y; acc[1][2] += a.y * b.z; acc[1][3] += a.y * b.w;
      acc[2][0] += a.z * b.x; acc[2][1] += a.z * b.y; acc[2][2] += a.z * b.z; acc[2][3] += a.z * b.w;
      acc[3][0] += a.w * b.x; acc[3][1] += a.w * b.y; acc[3][2] += a.w * b.z; acc[3][3] += a.w * b.w;
    }
  }

  // epilogue: + bias, remap to head-major [h*NB + b, seq, dh]
  const int h = bx;  // n0 = h*64
#pragma unroll
  for (int i = 0; i < 4; i++) {
    const int m = m0 + ty * 4 + i;
    const int bidx = m / NSEQ;
    const int seq = m - bidx * NSEQ;
    const size_t base = (((size_t)(h * NB + bidx)) * NSEQ + seq) * NDH + tx * 4;
#pragma unroll
    for (int j = 0; j < 4; j++) {
      const float v = acc[i][j] + bias[n0 + tx * 4 + j];
      outp[base + j] = __float2bfloat16(v);
    }
  }
}

// ---------------------------------------------------------------------------
// K2: attention. Block = (q-tile of 16, head-batch x). 256 threads.
// Scores = q . (k + pos_k[k - q + 539]), scaled 1/8, key-masked softmax, PV.
// q/k/v bf16, pos fp32, ctx fp32.
// v2: no full unroll (spill fix), VGPR cap 128, XOR-swizzled K/P/V tiles.
// ---------------------------------------------------------------------------
__global__ __launch_bounds__(256, 4) void attn(
    const bf16* __restrict__ qh, const bf16* __restrict__ kh,
    const bf16* __restrict__ vh, const float* __restrict__ pos,
    const int* __restrict__ vlen, float* __restrict__ ctx) {
  __shared__ float Qs[16][68];
  __shared__ float Ks[64][64];   // swizzled; reused for V in phase C
  __shared__ float Ps[80][64];   // swizzled
  __shared__ float S[16][545];
  __shared__ float red[16][17];

  const int tid = threadIdx.x;
  const int qb = blockIdx.x;  // 0..33
  const int x = blockIdx.y;   // 0..255  (x = h*NB + b)
  const int b = x & 31, h = x >> 5;
  const int q0 = qb * 16;
  const int valid = vlen[b];
  const bf16* qbase = qh + (size_t)x * NSEQ * NDH;
  const bf16* kbase = kh + (size_t)x * NSEQ * NDH;
  const bf16* vbase = vh + (size_t)x * NSEQ * NDH;

  // load Q tile (zero-fill rows past NSEQ)
  if (tid < 128) {
    const int row = tid >> 3, grp = tid & 7;
    const int q = q0 + row;
    float f[8];
    if (q < NSEQ) {
      load8(qbase + (size_t)q * NDH + grp * 8, f);
    } else {
#pragma unroll
      for (int i = 0; i < 8; i++) f[i] = 0.f;
    }
    *(float4*)&Qs[row][grp * 8] = make_float4(f[0], f[1], f[2], f[3]);
    *(float4*)&Qs[row][grp * 8 + 4] = make_float4(f[4], f[5], f[6], f[7]);
  }

  const int qq0 = (tid >> 5) * 2;   // 0..14
  const int kk0 = (tid & 31) * 2;   // 0..62
  const int pbase = kk0 - qq0 + 15; // 1..77

  // -------- phase A: scores --------
  for (int k0 = 0; k0 < NSEQ; k0 += 64) {
    const int ntile = min(64, NSEQ - k0);
    __syncthreads();  // previous compute done (also publishes Qs on iter 0)
    for (int u = tid; u < 512; u += 256) {
      const int row = u >> 3, grp = u & 7;
      const int kk = min(k0 + row, NSEQ - 1);
      float f[8];
      load8(kbase + (size_t)kk * NDH + grp * 8, f);
      *(float4*)&Ks[row][swz(row, grp * 2)] = make_float4(f[0], f[1], f[2], f[3]);
      *(float4*)&Ks[row][swz(row, grp * 2 + 1)] = make_float4(f[4], f[5], f[6], f[7]);
    }
    const int relmin = k0 - q0 + 524;  // (k0) - (q0+15) + 539
    for (int u = tid; u < 640; u += 256) {
      const int row = u >> 3, grp = u & 7;
      int g = relmin + row;
      g = max(0, min(NPOS - 1, g));  // clamped rows are never consumed
      float f[8];
      load8f(pos + (size_t)g * NDH + grp * 8, f);
      *(float4*)&Ps[row][swz(row, grp * 2)] = make_float4(f[0], f[1], f[2], f[3]);
      *(float4*)&Ps[row][swz(row, grp * 2 + 1)] = make_float4(f[4], f[5], f[6], f[7]);
    }
    __syncthreads();

    float a00 = 0.f, a01 = 0.f, a10 = 0.f, a11 = 0.f;
#pragma unroll 2
    for (int gd = 0; gd < 16; gd++) {
      const int d = gd * 4;
      const float4 qa = *(const float4*)&Qs[qq0][d];
      const float4 qc = *(const float4*)&Qs[qq0 + 1][d];
      const float4 ka = *(const float4*)&Ks[kk0][swz(kk0, gd)];
      const float4 kc = *(const float4*)&Ks[kk0 + 1][swz(kk0 + 1, gd)];
      const float4 pm = *(const float4*)&Ps[pbase - 1][swz(pbase - 1, gd)];
      const float4 p0 = *(const float4*)&Ps[pbase][swz(pbase, gd)];
      const float4 pp = *(const float4*)&Ps[pbase + 1][swz(pbase + 1, gd)];
      a00 += qa.x * (ka.x + p0.x) + qa.y * (ka.y + p0.y) + qa.z * (ka.z + p0.z) + qa.w * (ka.w + p0.w);
      a01 += qa.x * (kc.x + pp.x) + qa.y * (kc.y + pp.y) + qa.z * (kc.z + pp.z) + qa.w * (kc.w + pp.w);
      a10 += qc.x * (ka.x + pm.x) + qc.y * (ka.y + pm.y) + qc.z * (ka.z + pm.z) + qc.w * (ka.w + pm.w);
      a11 += qc.x * (kc.x + p0.x) + qc.y * (kc.y + p0.y) + qc.z * (kc.z + p0.z) + qc.w * (kc.w + p0.w);
    }
    if (kk0 < ntile) {
      S[qq0][k0 + kk0] = a00 * 0.125f;
      S[qq0 + 1][k0 + kk0] = a10 * 0.125f;
    }
    if (kk0 + 1 < ntile) {
      S[qq0][k0 + kk0 + 1] = a01 * 0.125f;
      S[qq0 + 1][k0 + kk0 + 1] = a11 * 0.125f;
    }
  }
  __syncthreads();

  // -------- phase B: masked softmax over k < valid --------
  const int r = tid >> 4, c = tid & 15;
  float ml = -1e30f;
  for (int k = c; k < valid; k += 16) ml = fmaxf(ml, S[r][k]);
  red[r][c] = ml;
  __syncthreads();
  if (c == 0) {
    float m = red[r][0];
#pragma unroll
    for (int i = 1; i < 16; i++) m = fmaxf(m, red[r][i]);
    red[r][16] = m;
  }
  __syncthreads();
  const float rowmax = red[r][16];
  float sl = 0.f;
  for (int k = c; k < valid; k += 16) {
    const float e = __expf(S[r][k] - rowmax);
    S[r][k] = e;
    sl += e;
  }
  red[r][c] = sl;
  __syncthreads();
  if (c == 0) {
    float s = 0.f;
#pragma unroll
    for (int i = 0; i < 16; i++) s += red[r][i];
    red[r][16] = 1.f / s;
  }
  __syncthreads();
  const float inv = red[r][16];
  for (int k = c; k < NSEQ; k += 16) S[r][k] = (k < valid) ? S[r][k] * inv : 0.f;

  // -------- phase C: out = P @ V --------
  float o0 = 0.f, o1 = 0.f, o2 = 0.f, o3 = 0.f;
  const int oq = tid >> 4;
  const int gv = tid & 15;       // float4 group in dh
  const int dh0 = gv * 4;
  for (int k0 = 0; k0 < NSEQ; k0 += 64) {
    const int ntile = min(64, NSEQ - k0);
    __syncthreads();  // previous compute done before overwriting Ks(=Vs)
    for (int u = tid; u < 512; u += 256) {
      const int row = u >> 3, grp = u & 7;
      const int kk = min(k0 + row, NSEQ - 1);
      float f[8];
      load8(vbase + (size_t)kk * NDH + grp * 8, f);
      *(float4*)&Ks[row][swz(row, grp * 2)] = make_float4(f[0], f[1], f[2], f[3]);
      *(float4*)&Ks[row][swz(row, grp * 2 + 1)] = make_float4(f[4], f[5], f[6], f[7]);
    }
    __syncthreads();
#pragma unroll 4
    for (int kk = 0; kk < ntile; kk++) {
      const float p = S[oq][k0 + kk];
      const float4 v4 = *(const float4*)&Ks[kk][swz(kk, gv)];
      o0 += p * v4.x;
      o1 += p * v4.y;
      o2 += p * v4.z;
      o3 += p * v4.w;
    }
  }
  const int q = q0 + oq;
  if (q < NSEQ) {
    const size_t off = ((size_t)b * NSEQ + q) * ND + h * NDH + dh0;
    *(float4*)&ctx[off] = make_float4(o0, o1, o2, o3);
  }
}

// ---------------------------------------------------------------------------
// K3: out projection + bias + residual. ctx[17280,512] @ Wh + bh + query
// all fp32.
// ---------------------------------------------------------------------------
__global__ __launch_bounds__(256) void out_proj(
    const float* __restrict__ ctx, const float* __restrict__ Wh,
    const float* __restrict__ bh, const float* __restrict__ query,
    float* __restrict__ tmp) {
  __shared__ float AsT[32][68];
  __shared__ float Bs[32][64];
  const int tid = threadIdx.x;
  const int bx = blockIdx.x;  // n-tile
  const int by = blockIdx.y;  // m-tile
  const int m0 = by * 64, n0 = bx * 64;
  const int tx = tid & 15, ty = tid >> 4;
  const int arow = tid >> 2, agrp = tid & 3;
  const int brow = tid >> 3, bgrp = tid & 7;

  float acc[4][4] = {};

  for (int k0 = 0; k0 < 512; k0 += 32) {
    float af[8], bfv[8];
    load8f(ctx + (size_t)(m0 + arow) * 512 + k0 + agrp * 8, af);
    load8f(Wh + (size_t)(k0 + brow) * 512 + n0 + bgrp * 8, bfv);
    __syncthreads();
#pragma unroll
    for (int i = 0; i < 8; i++) AsT[agrp * 8 + i][arow] = af[i];
    *(float4*)&Bs[brow][bgrp * 8] = make_float4(bfv[0], bfv[1], bfv[2], bfv[3]);
    *(float4*)&Bs[brow][bgrp * 8 + 4] = make_float4(bfv[4], bfv[5], bfv[6], bfv[7]);
    __syncthreads();
#pragma unroll
    for (int kk = 0; kk < 32; kk++) {
      const float4 a = *(const float4*)&AsT[kk][ty * 4];
      const float4 b = *(const float4*)&Bs[kk][tx * 4];
      acc[0][0] += a.x * b.x; acc[0][1] += a.x * b.y; acc[0][2] += a.x * b.z; acc[0][3] += a.x * b.w;
      acc[1][0] += a.y * b.x; acc[1][1] += a.y * b.y; acc[1][2] += a.y * b.z; acc[1][3] += a.y * b.w;
      acc[2][0] += a.z * b.x; acc[2][1] += a.z * b.y; acc[2][2] += a.z * b.z; acc[2][3] += a.z * b.w;
      acc[3][0] += a.w * b.x; acc[3][1] += a.w * b.y; acc[3][2] += a.w * b.z; acc[3][3] += a.w * b.w;
    }
  }

#pragma unroll
  for (int i = 0; i < 4; i++) {
    const int m = m0 + ty * 4 + i;
    const size_t off = (size_t)m * 512 + n0 + tx * 4;
    const float4 qv = *(const float4*)&query[off];
    float4 rv;
    rv.x = acc[i][0] + bh[n0 + tx * 4 + 0] + qv.x;
    rv.y = acc[i][1] + bh[n0 + tx * 4 + 1] + qv.y;
    rv.z = acc[i][2] + bh[n0 + tx * 4 + 2] + qv.z;
    rv.w = acc[i][3] + bh[n0 + tx * 4 + 3] + qv.w;
    *(float4*)&tmp[off] = rv;
  }
}

// ---------------------------------------------------------------------------
// K4: layernorm over D=512, eps=1e-7. One block per row, 256 threads x 2 elems.
// ---------------------------------------------------------------------------
__global__ __launch_bounds__(256) void lnorm(
    const float* __restrict__ tmp, const float* __restrict__ gamma,
    const float* __restrict__ beta, float* __restrict__ out) {
  __shared__ float sred[256];
  const int row = blockIdx.x;
  const int tid = threadIdx.x;
  const size_t base = (size_t)row * 512;
  const float x0 = tmp[base + tid];
  const float x1 = tmp[base + 256 + tid];

  sred[tid] = x0 + x1;
  __syncthreads();
  for (int o = 128; o > 0; o >>= 1) {
    if (tid < o) sred[tid] += sred[tid + o];
    __syncthreads();
  }
  const float mean = sred[0] * (1.f / 512.f);
  __syncthreads();
  const float d0 = x0 - mean, d1 = x1 - mean;
  sred[tid] = d0 * d0 + d1 * d1;
  __syncthreads();
  for (int o = 128; o > 0; o >>= 1) {
    if (tid < o) sred[tid] += sred[tid + o];
    __syncthreads();
  }
  const float var = sred[0] * (1.f / 512.f);
  const float rstd = rsqrtf(var + 1e-7f);
  out[base + tid] = d0 * rstd * gamma[tid] + beta[tid];
  out[base + 256 + tid] = d1 * rstd * gamma[tid + 256] + beta[tid + 256];
}

// ---------------------------------------------------------------------------
// Workspace: q/k/v head-major bf16 = 3 x 17.7 MB = 53.1 MB.
// ctx (fp32) lives in d_out (exactly out-sized); pre-LN tmp (fp32) reuses the
// qh+kh region (35.4 MB, dead after attn); lnorm writes final fp32 to d_out.
// ---------------------------------------------------------------------------
extern "C" void kernel_launch(void* const* d_in, const int* in_sizes, int n_in,
                              void* d_out, int out_size, void* d_ws, size_t ws_size,
                              hipStream_t stream) {
  const float* query = (const float*)d_in[0];
  const float* Wq = (const float*)d_in[1];
  const float* bq = (const float*)d_in[2];
  const float* Wk = (const float*)d_in[3];
  const float* bk = (const float*)d_in[4];
  const float* Wv = (const float*)d_in[5];
  const float* bv = (const float*)d_in[6];
  const float* Wh = (const float*)d_in[7];
  const float* bh = (const float*)d_in[8];
  const float* pos = (const float*)d_in[9];
  const float* gamma = (const float*)d_in[10];
  const float* beta = (const float*)d_in[11];
  const int* vlen = (const int*)d_in[12];

  bf16* ws = (bf16*)d_ws;
  const size_t QSZ = (size_t)NHB * NSEQ * NDH;  // 8,847,360 elems
  bf16* qh = ws;
  bf16* kh = ws + QSZ;
  bf16* vh = ws + 2 * QSZ;
  float* ctx = (float*)d_out;  // d_out doubles as ctx scratch
  float* tmp = (float*)d_ws;   // reuse qh+kh region (dead after attn), 35.4 MB
  (void)ws_size;

  qkv_proj<<<dim3(8, 270, 3), 256, 0, stream>>>(query, Wq, bq, Wk, bk, Wv, bv, qh, kh, vh);
  attn<<<dim3(34, 256), 256, 0, stream>>>(qh, kh, vh, pos, vlen, ctx);
  out_proj<<<dim3(8, 270), 256, 0, stream>>>(ctx, Wh, bh, query, tmp);
  lnorm<<<NM, 256, 0, stream>>>(tmp, gamma, beta, (float*)d_out);
}

// Round 5
// 1044.711 us; speedup vs baseline: 13.7736x; 1.4789x over previous
//
#include <hip/hip_runtime.h>
#include <hip/hip_bf16.h>

typedef __hip_bfloat16 bf16;

// Problem constants
#define NB 32      // batch
#define NSEQ 540   // sequence length
#define ND 512     // model dim
#define NH 8       // heads
#define NDH 64     // head dim
#define NHB 256    // NH*NB
#define NM 17280   // NB*NSEQ
#define NPOS 1079  // 2*539+1

// MFMA types (gfx950 v_mfma_f32_16x16x32_bf16)
typedef __bf16 v8bf __attribute__((ext_vector_type(8)));
typedef float f32x4 __attribute__((ext_vector_type(4)));

union U8 {
  uint4 u;
  unsigned short s[8];
  v8bf v;
};

__device__ __forceinline__ unsigned short f2b(float x) {  // RNE fp32->bf16 bits
  union { float f; unsigned u; } c;
  c.f = x;
  const unsigned r = c.u + 0x7fffu + ((c.u >> 16) & 1u);
  return (unsigned short)(r >> 16);
}

// fp32x8 -> 8 floats (two 16B loads)
__device__ __forceinline__ void load8f(const float* __restrict__ p, float* f) {
  const float4 a = *reinterpret_cast<const float4*>(p);
  const float4 b = *reinterpret_cast<const float4*>(p + 4);
  f[0] = a.x; f[1] = a.y; f[2] = a.z; f[3] = a.w;
  f[4] = b.x; f[5] = b.y; f[6] = b.z; f[7] = b.w;
}

// ---------------------------------------------------------------------------
// K1: QKV projection.  X[17280,512] @ W[512,512] + b  -> head-major [H*B,N,DH]
// fp32 in, bf16 out. 64x64 tile, BK=32, 256 threads, 4x4 per thread.
// (unchanged from round 4)
// ---------------------------------------------------------------------------
__global__ __launch_bounds__(256) void qkv_proj(
    const float* __restrict__ X,
    const float* __restrict__ Wq, const float* __restrict__ bq,
    const float* __restrict__ Wk, const float* __restrict__ bk,
    const float* __restrict__ Wv, const float* __restrict__ bv,
    bf16* __restrict__ qh, bf16* __restrict__ kh, bf16* __restrict__ vh) {
  __shared__ float AsT[32][68];  // [k][m], padded
  __shared__ float Bs[32][64];   // [k][n]
  const int tid = threadIdx.x;
  const int bx = blockIdx.x;   // n-tile == head (0..7)
  const int by = blockIdx.y;   // m-tile (0..269)
  const int sel = blockIdx.z;  // 0=q 1=k 2=v
  const float* W = (sel == 0) ? Wq : ((sel == 1) ? Wk : Wv);
  const float* bias = (sel == 0) ? bq : ((sel == 1) ? bk : bv);
  bf16* outp = (sel == 0) ? qh : ((sel == 1) ? kh : vh);
  const int m0 = by * 64, n0 = bx * 64;
  const int tx = tid & 15, ty = tid >> 4;
  const int arow = tid >> 2, agrp = tid & 3;
  const int brow = tid >> 3, bgrp = tid & 7;

  float acc[4][4] = {};

  for (int k0 = 0; k0 < 512; k0 += 32) {
    float af[8], bfv[8];
    load8f(X + (size_t)(m0 + arow) * 512 + k0 + agrp * 8, af);
    load8f(W + (size_t)(k0 + brow) * 512 + n0 + bgrp * 8, bfv);
    __syncthreads();
#pragma unroll
    for (int i = 0; i < 8; i++) AsT[agrp * 8 + i][arow] = af[i];
    *(float4*)&Bs[brow][bgrp * 8] = make_float4(bfv[0], bfv[1], bfv[2], bfv[3]);
    *(float4*)&Bs[brow][bgrp * 8 + 4] = make_float4(bfv[4], bfv[5], bfv[6], bfv[7]);
    __syncthreads();
#pragma unroll
    for (int kk = 0; kk < 32; kk++) {
      const float4 a = *(const float4*)&AsT[kk][ty * 4];
      const float4 b = *(const float4*)&Bs[kk][tx * 4];
      acc[0][0] += a.x * b.x; acc[0][1] += a.x * b.y; acc[0][2] += a.x * b.z; acc[0][3] += a.x * b.w;
      acc[1][0] += a.y * b.x; acc[1][1] += a.y * b.y; acc[1][2] += a.y * b.z; acc[1][3] += a.y * b.w;
      acc[2][0] += a.z * b.x; acc[2][1] += a.z * b.y; acc[2][2] += a.z * b.z; acc[2][3] += a.z * b.w;
      acc[3][0] += a.w * b.x; acc[3][1] += a.w * b.y; acc[3][2] += a.w * b.z; acc[3][3] += a.w * b.w;
    }
  }

  const int h = bx;
#pragma unroll
  for (int i = 0; i < 4; i++) {
    const int m = m0 + ty * 4 + i;
    const int bidx = m / NSEQ;
    const int seq = m - bidx * NSEQ;
    const size_t base = (((size_t)(h * NB + bidx)) * NSEQ + seq) * NDH + tx * 4;
#pragma unroll
    for (int j = 0; j < 4; j++) {
      const float v = acc[i][j] + bias[n0 + tx * 4 + j];
      outp[base + j] = __float2bfloat16(v);
    }
  }
}

// ---------------------------------------------------------------------------
// K2: attention, MFMA version.
// Block = (q-tile of 16, head-batch x), 256 threads = 4 waves.
// Phase A: per 64-key tile, QK^T and T = Q @ posSlice^T via
//   v_mfma_f32_16x16x32_bf16; S = (QK + gather(T)) / 8 into LDS.
// Phase B: masked softmax (exclusion for k >= valid; zeros cols [valid,576)).
// Phase C: O = P @ V, V staged transposed so B-frags are ds_read_b128.
// Fragment layouts (m89-verified): A[m=lane&15][k=(lane>>4)*8+j],
// B[k=(lane>>4)*8+j][n=lane&15], C/D[m=(lane>>4)*4+reg][n=lane&15].
// ---------------------------------------------------------------------------
#define SW 580  // S row stride (floats): 16B-aligned rows, bank offset 4/row
#define KP 72   // K/V/pos LDS row pitch (ushorts): 16B-aligned rows

__global__ __launch_bounds__(256, 2) void attn(
    const bf16* __restrict__ qh, const bf16* __restrict__ kh,
    const bf16* __restrict__ vh, const float* __restrict__ pos,
    const int* __restrict__ vlen, float* __restrict__ ctx) {
  __shared__ float S[16][SW];            // 37.1 KB  scores -> P
  __shared__ unsigned short KV[64][KP];  //  9.2 KB  K tile / V^T tile
  __shared__ unsigned short Ps[80][KP];  // 11.5 KB  pos slice tile
  __shared__ float Tt[16][84];           //  5.4 KB  T = Q @ posSlice^T
  __shared__ float red[16][17];          //  1.1 KB

  const int tid = threadIdx.x;
  const int lane = tid & 63;
  const int w = tid >> 6;       // wave 0..3
  const int l15 = lane & 15;
  const int quad = lane >> 4;   // 0..3
  const int qb = blockIdx.x;    // 0..33
  const int x = blockIdx.y;     // 0..255 (x = h*NB + b)
  const int b = x & 31, h = x >> 5;
  const int q0 = qb * 16;
  const int valid = vlen[b];
  const bf16* qbase = qh + (size_t)x * NSEQ * NDH;
  const bf16* kbase = kh + (size_t)x * NSEQ * NDH;
  const bf16* vbase = vh + (size_t)x * NSEQ * NDH;

  // Q A-fragments (2 K-chunks of 32), zero-filled rows past NSEQ
  U8 aq0, aq1;
  {
    const int q = q0 + l15;
    if (q < NSEQ) {
      aq0.u = *(const uint4*)(qbase + (size_t)q * NDH + quad * 8);
      aq1.u = *(const uint4*)(qbase + (size_t)q * NDH + 32 + quad * 8);
    } else {
      aq0.u = make_uint4(0, 0, 0, 0);
      aq1.u = make_uint4(0, 0, 0, 0);
    }
  }

  // -------- phase A: scores --------
  for (int k0 = 0; k0 < NSEQ; k0 += 64) {
    __syncthreads();  // prior iteration's Tt/KV consumers done
    // stage K tile [64 keys][64 d] bf16 (clamped rows never survive masking)
    for (int u = tid; u < 512; u += 256) {
      const int row = u >> 3, g = u & 7;
      const int kk = min(k0 + row, NSEQ - 1);
      *(uint4*)&KV[row][g * 8] = *(const uint4*)(kbase + (size_t)kk * NDH + g * 8);
    }
    // stage pos slice rows r0..r0+79 (fp32 -> bf16), clamped rows unconsumed
    const int r0 = k0 - q0 + 524;  // rel(q=q0+15, k=k0)
    for (int u = tid; u < 640; u += 256) {
      const int row = u >> 3, g = u & 7;
      int grow = r0 + row;
      grow = max(0, min(NPOS - 1, grow));
      float f[8];
      load8f(pos + (size_t)grow * NDH + g * 8, f);
      U8 p;
#pragma unroll
      for (int j = 0; j < 8; j++) p.s[j] = f2b(f[j]);
      *(uint4*)&Ps[row][g * 8] = p.u;
    }
    __syncthreads();

    // QK: wave w owns key-subtile w (keys w*16 .. w*16+15)
    f32x4 accqk = {0.f, 0.f, 0.f, 0.f};
    {
      U8 bk;
      bk.u = *(const uint4*)&KV[w * 16 + l15][quad * 8];
      accqk = __builtin_amdgcn_mfma_f32_16x16x32_bf16(aq0.v, bk.v, accqk, 0, 0, 0);
      bk.u = *(const uint4*)&KV[w * 16 + l15][32 + quad * 8];
      accqk = __builtin_amdgcn_mfma_f32_16x16x32_bf16(aq1.v, bk.v, accqk, 0, 0, 0);
    }
    // T: 5 r-subtiles; wave w owns rsub w, wave 0 also rsub 4
    {
      f32x4 accT = {0.f, 0.f, 0.f, 0.f};
      U8 bp;
      bp.u = *(const uint4*)&Ps[w * 16 + l15][quad * 8];
      accT = __builtin_amdgcn_mfma_f32_16x16x32_bf16(aq0.v, bp.v, accT, 0, 0, 0);
      bp.u = *(const uint4*)&Ps[w * 16 + l15][32 + quad * 8];
      accT = __builtin_amdgcn_mfma_f32_16x16x32_bf16(aq1.v, bp.v, accT, 0, 0, 0);
#pragma unroll
      for (int i = 0; i < 4; i++) Tt[quad * 4 + i][w * 16 + l15] = accT[i];
      if (w == 0) {
        f32x4 accT2 = {0.f, 0.f, 0.f, 0.f};
        bp.u = *(const uint4*)&Ps[64 + l15][quad * 8];
        accT2 = __builtin_amdgcn_mfma_f32_16x16x32_bf16(aq0.v, bp.v, accT2, 0, 0, 0);
        bp.u = *(const uint4*)&Ps[64 + l15][32 + quad * 8];
        accT2 = __builtin_amdgcn_mfma_f32_16x16x32_bf16(aq1.v, bp.v, accT2, 0, 0, 0);
#pragma unroll
        for (int i = 0; i < 4; i++) Tt[quad * 4 + i][64 + l15] = accT2[i];
      }
    }
    __syncthreads();  // Tt complete
    // S = (QK + T[q][kk + 15 - qq]) / 8
    {
      const int kk = w * 16 + l15;
#pragma unroll
      for (int i = 0; i < 4; i++) {
        const int qq = quad * 4 + i;
        S[qq][k0 + kk] = (accqk[i] + Tt[qq][kk + 15 - qq]) * 0.125f;
      }
    }
  }
  __syncthreads();

  // -------- phase B: masked softmax over k < valid --------
  {
    const int r = tid >> 4, c = tid & 15;
    float ml = -1e30f;
    for (int k = c; k < valid; k += 16) ml = fmaxf(ml, S[r][k]);
    red[r][c] = ml;
    __syncthreads();
    if (c == 0) {
      float m = red[r][0];
#pragma unroll
      for (int i = 1; i < 16; i++) m = fmaxf(m, red[r][i]);
      red[r][16] = m;
    }
    __syncthreads();
    const float rowmax = red[r][16];
    float sl = 0.f;
    for (int k = c; k < valid; k += 16) {
      const float e = __expf(S[r][k] - rowmax);
      S[r][k] = e;
      sl += e;
    }
    red[r][c] = sl;
    __syncthreads();
    if (c == 0) {
      float s = 0.f;
#pragma unroll
      for (int i = 0; i < 16; i++) s += red[r][i];
      red[r][16] = 1.f / s;
    }
    __syncthreads();
    const float inv = red[r][16];
    for (int k = c; k < 576; k += 16) S[r][k] = (k < valid) ? S[r][k] * inv : 0.f;
  }

  // -------- phase C: O = P @ V (V staged transposed) --------
  f32x4 acco = {0.f, 0.f, 0.f, 0.f};  // wave w owns dh-subtile w
  for (int k0 = 0; k0 < NSEQ; k0 += 64) {
    __syncthreads();  // phase-B writes done (iter 0) / prior PV reads done
#pragma unroll
    for (int t = 0; t < 2; t++) {
      const int key = tid & 63;
      const int g = (tid >> 6) + t * 4;
      const int kk = min(k0 + key, NSEQ - 1);
      U8 vv;
      vv.u = *(const uint4*)(vbase + (size_t)kk * NDH + g * 8);
#pragma unroll
      for (int j = 0; j < 8; j++) KV[g * 8 + j][key] = vv.s[j];  // V^T[dh][key]
    }
    __syncthreads();
#pragma unroll
    for (int c = 0; c < 2; c++) {
      const float* srow = &S[l15][k0 + c * 32 + quad * 8];
      const float4 pa = *(const float4*)srow;
      const float4 pb = *(const float4*)(srow + 4);
      U8 ap;
      ap.s[0] = f2b(pa.x); ap.s[1] = f2b(pa.y); ap.s[2] = f2b(pa.z); ap.s[3] = f2b(pa.w);
      ap.s[4] = f2b(pb.x); ap.s[5] = f2b(pb.y); ap.s[6] = f2b(pb.z); ap.s[7] = f2b(pb.w);
      U8 bv;
      bv.u = *(const uint4*)&KV[w * 16 + l15][c * 32 + quad * 8];
      acco = __builtin_amdgcn_mfma_f32_16x16x32_bf16(ap.v, bv.v, acco, 0, 0, 0);
    }
  }
  // store O: lane reg i -> O[q=quad*4+i][dh=w*16+l15]
#pragma unroll
  for (int i = 0; i < 4; i++) {
    const int q = q0 + quad * 4 + i;
    if (q < NSEQ) {
      ctx[((size_t)b * NSEQ + q) * ND + h * NDH + w * 16 + l15] = acco[i];
    }
  }
}

// ---------------------------------------------------------------------------
// K3: out projection + bias + residual. ctx[17280,512] @ Wh + bh + query
// (unchanged from round 4)
// ---------------------------------------------------------------------------
__global__ __launch_bounds__(256) void out_proj(
    const float* __restrict__ ctx, const float* __restrict__ Wh,
    const float* __restrict__ bh, const float* __restrict__ query,
    float* __restrict__ tmp) {
  __shared__ float AsT[32][68];
  __shared__ float Bs[32][64];
  const int tid = threadIdx.x;
  const int bx = blockIdx.x;
  const int by = blockIdx.y;
  const int m0 = by * 64, n0 = bx * 64;
  const int tx = tid & 15, ty = tid >> 4;
  const int arow = tid >> 2, agrp = tid & 3;
  const int brow = tid >> 3, bgrp = tid & 7;

  float acc[4][4] = {};

  for (int k0 = 0; k0 < 512; k0 += 32) {
    float af[8], bfv[8];
    load8f(ctx + (size_t)(m0 + arow) * 512 + k0 + agrp * 8, af);
    load8f(Wh + (size_t)(k0 + brow) * 512 + n0 + bgrp * 8, bfv);
    __syncthreads();
#pragma unroll
    for (int i = 0; i < 8; i++) AsT[agrp * 8 + i][arow] = af[i];
    *(float4*)&Bs[brow][bgrp * 8] = make_float4(bfv[0], bfv[1], bfv[2], bfv[3]);
    *(float4*)&Bs[brow][bgrp * 8 + 4] = make_float4(bfv[4], bfv[5], bfv[6], bfv[7]);
    __syncthreads();
#pragma unroll
    for (int kk = 0; kk < 32; kk++) {
      const float4 a = *(const float4*)&AsT[kk][ty * 4];
      const float4 b = *(const float4*)&Bs[kk][tx * 4];
      acc[0][0] += a.x * b.x; acc[0][1] += a.x * b.y; acc[0][2] += a.x * b.z; acc[0][3] += a.x * b.w;
      acc[1][0] += a.y * b.x; acc[1][1] += a.y * b.y; acc[1][2] += a.y * b.z; acc[1][3] += a.y * b.w;
      acc[2][0] += a.z * b.x; acc[2][1] += a.z * b.y; acc[2][2] += a.z * b.z; acc[2][3] += a.z * b.w;
      acc[3][0] += a.w * b.x; acc[3][1] += a.w * b.y; acc[3][2] += a.w * b.z; acc[3][3] += a.w * b.w;
    }
  }

#pragma unroll
  for (int i = 0; i < 4; i++) {
    const int m = m0 + ty * 4 + i;
    const size_t off = (size_t)m * 512 + n0 + tx * 4;
    const float4 qv = *(const float4*)&query[off];
    float4 rv;
    rv.x = acc[i][0] + bh[n0 + tx * 4 + 0] + qv.x;
    rv.y = acc[i][1] + bh[n0 + tx * 4 + 1] + qv.y;
    rv.z = acc[i][2] + bh[n0 + tx * 4 + 2] + qv.z;
    rv.w = acc[i][3] + bh[n0 + tx * 4 + 3] + qv.w;
    *(float4*)&tmp[off] = rv;
  }
}

// ---------------------------------------------------------------------------
// K4: layernorm over D=512, eps=1e-7. (unchanged from round 4)
// ---------------------------------------------------------------------------
__global__ __launch_bounds__(256) void lnorm(
    const float* __restrict__ tmp, const float* __restrict__ gamma,
    const float* __restrict__ beta, float* __restrict__ out) {
  __shared__ float sred[256];
  const int row = blockIdx.x;
  const int tid = threadIdx.x;
  const size_t base = (size_t)row * 512;
  const float x0 = tmp[base + tid];
  const float x1 = tmp[base + 256 + tid];

  sred[tid] = x0 + x1;
  __syncthreads();
  for (int o = 128; o > 0; o >>= 1) {
    if (tid < o) sred[tid] += sred[tid + o];
    __syncthreads();
  }
  const float mean = sred[0] * (1.f / 512.f);
  __syncthreads();
  const float d0 = x0 - mean, d1 = x1 - mean;
  sred[tid] = d0 * d0 + d1 * d1;
  __syncthreads();
  for (int o = 128; o > 0; o >>= 1) {
    if (tid < o) sred[tid] += sred[tid + o];
    __syncthreads();
  }
  const float var = sred[0] * (1.f / 512.f);
  const float rstd = rsqrtf(var + 1e-7f);
  out[base + tid] = d0 * rstd * gamma[tid] + beta[tid];
  out[base + 256 + tid] = d1 * rstd * gamma[tid + 256] + beta[tid + 256];
}

// ---------------------------------------------------------------------------
// Workspace: q/k/v head-major bf16 = 3 x 17.7 MB = 53.1 MB.
// ctx (fp32) lives in d_out; pre-LN tmp (fp32) reuses the qh+kh region
// (dead after attn); lnorm writes final fp32 to d_out.
// ---------------------------------------------------------------------------
extern "C" void kernel_launch(void* const* d_in, const int* in_sizes, int n_in,
                              void* d_out, int out_size, void* d_ws, size_t ws_size,
                              hipStream_t stream) {
  const float* query = (const float*)d_in[0];
  const float* Wq = (const float*)d_in[1];
  const float* bq = (const float*)d_in[2];
  const float* Wk = (const float*)d_in[3];
  const float* bk = (const float*)d_in[4];
  const float* Wv = (const float*)d_in[5];
  const float* bv = (const float*)d_in[6];
  const float* Wh = (const float*)d_in[7];
  const float* bh = (const float*)d_in[8];
  const float* pos = (const float*)d_in[9];
  const float* gamma = (const float*)d_in[10];
  const float* beta = (const float*)d_in[11];
  const int* vlen = (const int*)d_in[12];

  bf16* ws = (bf16*)d_ws;
  const size_t QSZ = (size_t)NHB * NSEQ * NDH;  // 8,847,360 elems
  bf16* qh = ws;
  bf16* kh = ws + QSZ;
  bf16* vh = ws + 2 * QSZ;
  float* ctx = (float*)d_out;
  float* tmp = (float*)d_ws;
  (void)ws_size;

  qkv_proj<<<dim3(8, 270, 3), 256, 0, stream>>>(query, Wq, bq, Wk, bk, Wv, bv, qh, kh, vh);
  attn<<<dim3(34, 256), 256, 0, stream>>>(qh, kh, vh, pos, vlen, ctx);
  out_proj<<<dim3(8, 270), 256, 0, stream>>>(ctx, Wh, bh, query, tmp);
  lnorm<<<NM, 256, 0, stream>>>(tmp, gamma, beta, (float*)d_out);
}

// Round 6
// 804.769 us; speedup vs baseline: 17.8802x; 1.2982x over previous
//
#include <hip/hip_runtime.h>
#include <hip/hip_bf16.h>

typedef __hip_bfloat16 bf16;

// Problem constants
#define NB 32      // batch
#define NSEQ 540   // sequence length
#define ND 512     // model dim
#define NH 8       // heads
#define NDH 64     // head dim
#define NHB 256    // NH*NB
#define NM 17280   // NB*NSEQ
#define NPOS 1079  // 2*539+1

// MFMA types (gfx950 v_mfma_f32_16x16x32_bf16)
typedef __bf16 v8bf __attribute__((ext_vector_type(8)));
typedef float f32x4 __attribute__((ext_vector_type(4)));

union U8 {
  uint4 u;
  unsigned short s[8];
  v8bf v;
};

__device__ __forceinline__ unsigned short f2b(float x) {  // RNE fp32->bf16 bits
  union { float f; unsigned u; } c;
  c.f = x;
  const unsigned r = c.u + 0x7fffu + ((c.u >> 16) & 1u);
  return (unsigned short)(r >> 16);
}

__device__ __forceinline__ float b2f16(unsigned short s) {
  return __uint_as_float(((unsigned)s) << 16);
}

// fp32x8 -> 8 floats (two 16B loads)
__device__ __forceinline__ void load8f(const float* __restrict__ p, float* f) {
  const float4 a = *reinterpret_cast<const float4*>(p);
  const float4 b = *reinterpret_cast<const float4*>(p + 4);
  f[0] = a.x; f[1] = a.y; f[2] = a.z; f[3] = a.w;
  f[4] = b.x; f[5] = b.y; f[6] = b.z; f[7] = b.w;
}

// ---------------------------------------------------------------------------
// K0: one-time pos fp32 -> bf16 (removes 256x-redundant per-block conversion)
// ---------------------------------------------------------------------------
__global__ __launch_bounds__(256) void pos_cvt(const float* __restrict__ pos,
                                              unsigned short* __restrict__ posb) {
  const int i = blockIdx.x * 256 + threadIdx.x;
  if (i < NPOS * NDH) posb[i] = f2b(pos[i]);
}

// ---------------------------------------------------------------------------
// K1: QKV projection.  X[17280,512] @ W[512,512] + b.
// q,k -> head-major [H*B, N, DH] bf16.  v -> TRANSPOSED vt[H*B, DH, N] bf16
// (so attention phase C can B-frag-load V^T directly from global).
// ---------------------------------------------------------------------------
__global__ __launch_bounds__(256) void qkv_proj(
    const float* __restrict__ X,
    const float* __restrict__ Wq, const float* __restrict__ bq,
    const float* __restrict__ Wk, const float* __restrict__ bk,
    const float* __restrict__ Wv, const float* __restrict__ bv,
    bf16* __restrict__ qh, bf16* __restrict__ kh, bf16* __restrict__ vt) {
  __shared__ float smem[4224];  // AsT[32][68] + Bs[32][64]; reused as Ts[64][66]
  float (*AsT)[68] = (float(*)[68])smem;
  float (*Bs)[64] = (float(*)[64])(smem + 2176);
  const int tid = threadIdx.x;
  const int bx = blockIdx.x;   // n-tile == head (0..7)
  const int by = blockIdx.y;   // m-tile (0..269)
  const int sel = blockIdx.z;  // 0=q 1=k 2=v
  const float* W = (sel == 0) ? Wq : ((sel == 1) ? Wk : Wv);
  const float* bias = (sel == 0) ? bq : ((sel == 1) ? bk : bv);
  const int m0 = by * 64, n0 = bx * 64;
  const int tx = tid & 15, ty = tid >> 4;
  const int arow = tid >> 2, agrp = tid & 3;
  const int brow = tid >> 3, bgrp = tid & 7;
  const int h = bx;

  float acc[4][4] = {};

  for (int k0 = 0; k0 < 512; k0 += 32) {
    float af[8], bfv[8];
    load8f(X + (size_t)(m0 + arow) * 512 + k0 + agrp * 8, af);
    load8f(W + (size_t)(k0 + brow) * 512 + n0 + bgrp * 8, bfv);
    __syncthreads();
#pragma unroll
    for (int i = 0; i < 8; i++) AsT[agrp * 8 + i][arow] = af[i];
    *(float4*)&Bs[brow][bgrp * 8] = make_float4(bfv[0], bfv[1], bfv[2], bfv[3]);
    *(float4*)&Bs[brow][bgrp * 8 + 4] = make_float4(bfv[4], bfv[5], bfv[6], bfv[7]);
    __syncthreads();
#pragma unroll
    for (int kk = 0; kk < 32; kk++) {
      const float4 a = *(const float4*)&AsT[kk][ty * 4];
      const float4 b = *(const float4*)&Bs[kk][tx * 4];
      acc[0][0] += a.x * b.x; acc[0][1] += a.x * b.y; acc[0][2] += a.x * b.z; acc[0][3] += a.x * b.w;
      acc[1][0] += a.y * b.x; acc[1][1] += a.y * b.y; acc[1][2] += a.y * b.z; acc[1][3] += a.y * b.w;
      acc[2][0] += a.z * b.x; acc[2][1] += a.z * b.y; acc[2][2] += a.z * b.z; acc[2][3] += a.z * b.w;
      acc[3][0] += a.w * b.x; acc[3][1] += a.w * b.y; acc[3][2] += a.w * b.z; acc[3][3] += a.w * b.w;
    }
  }

  if (sel != 2) {
    // q/k epilogue: head-major [h*NB + b, seq, dh]
    bf16* outp = (sel == 0) ? qh : kh;
#pragma unroll
    for (int i = 0; i < 4; i++) {
      const int m = m0 + ty * 4 + i;
      const int bidx = m / NSEQ;
      const int seq = m - bidx * NSEQ;
      const size_t base = (((size_t)(h * NB + bidx)) * NSEQ + seq) * NDH + tx * 4;
#pragma unroll
      for (int j = 0; j < 4; j++) {
        outp[base + j] = __float2bfloat16(acc[i][j] + bias[n0 + tx * 4 + j]);
      }
    }
  } else {
    // v epilogue: transpose through LDS, store vt[x][dh][seq]
    __syncthreads();  // main-loop LDS dead
    float (*Ts)[66] = (float(*)[66])smem;
#pragma unroll
    for (int i = 0; i < 4; i++)
#pragma unroll
      for (int j = 0; j < 4; j++)
        Ts[tx * 4 + j][ty * 4 + i] = acc[i][j] + bias[n0 + tx * 4 + j];
    __syncthreads();
    const int row = tid >> 2;  // dh 0..63
    const int seg = tid & 3;   // 16-token segment
    unsigned short* vts = (unsigned short*)vt;
#pragma unroll
    for (int g = 0; g < 2; g++) {
      const int mloc = seg * 16 + g * 8;
      const int mg = m0 + mloc;
      const int bA = mg / NSEQ, bB = (mg + 7) / NSEQ;
      unsigned short pk[8];
#pragma unroll
      for (int t = 0; t < 8; t++) pk[t] = f2b(Ts[row][mloc + t]);
      if (bA == bB) {
        const int seq = mg - bA * NSEQ;  // multiple of 4 -> 8B aligned
        unsigned short* dst = vts + (((size_t)(h * NB + bA)) * 64 + row) * NSEQ + seq;
        *(uint2*)dst = *(uint2*)pk;
        *(uint2*)(dst + 4) = *(uint2*)(pk + 4);
      } else {
#pragma unroll
        for (int t = 0; t < 8; t++) {
          const int m = mg + t;
          const int bb = m / NSEQ;
          vts[(((size_t)(h * NB + bb)) * 64 + row) * NSEQ + (m - bb * NSEQ)] = pk[t];
        }
      }
    }
  }
}

// ---------------------------------------------------------------------------
// K2: attention v3. Block = (q-tile of 16, head-batch x), 4 waves.
// No K/pos/V LDS staging: MFMA B-frags are contiguous 16B row chunks loaded
// directly from global (L2-resident). Scores kept as bf16 in LDS (P), fp32
// accum. Phase A: 1 barrier/k-tile (double-buffered Tt). Phase C: 0 barriers.
// Fragment layouts (m89-verified): A[m=lane&15][k=quad*8+j],
// B[k=quad*8+j][n=lane&15], C/D[m=quad*4+reg][n=lane&15].
// ---------------------------------------------------------------------------
#define PW 584  // P row stride (ushorts): 1168B rows -> 4-bank row advance

__global__ __launch_bounds__(256, 4) void attn(
    const bf16* __restrict__ qh, const bf16* __restrict__ kh,
    const bf16* __restrict__ vt, const unsigned short* __restrict__ posb,
    const int* __restrict__ vlen, float* __restrict__ ctx) {
  __shared__ unsigned short P[16][PW];  // 18.7 KB scores -> probabilities (bf16)
  __shared__ float Tt[2][16][84];       // 10.9 KB T = Q @ posSlice^T (dbuf)
  __shared__ float red[16][17];         //  1.1 KB

  const int tid = threadIdx.x;
  const int lane = tid & 63;
  const int w = tid >> 6;      // wave 0..3
  const int l15 = lane & 15;
  const int quad = lane >> 4;  // 0..3
  const int qb = blockIdx.x;   // 0..33
  const int x = blockIdx.y;    // 0..255 (x = h*NB + b)
  const int b = x & 31, h = x >> 5;
  const int q0 = qb * 16;
  const int valid = vlen[b];
  const bf16* qbase = qh + (size_t)x * NSEQ * NDH;
  const unsigned short* kbase = (const unsigned short*)(kh + (size_t)x * NSEQ * NDH);
  const unsigned short* vbase = (const unsigned short*)(vt + (size_t)x * NDH * NSEQ);

  // Q A-fragments (2 K-chunks of 32), zero-filled rows past NSEQ
  U8 aq0, aq1;
  {
    const int q = q0 + l15;
    if (q < NSEQ) {
      aq0.u = *(const uint4*)(qbase + (size_t)q * NDH + quad * 8);
      aq1.u = *(const uint4*)(qbase + (size_t)q * NDH + 32 + quad * 8);
    } else {
      aq0.u = make_uint4(0, 0, 0, 0);
      aq1.u = make_uint4(0, 0, 0, 0);
    }
  }

  // -------- phase A: scores --------
  for (int kt = 0; kt < 9; kt++) {
    const int k0 = kt * 64;
    const int buf = kt & 1;
    // QK: wave w owns key-subtile w. B-frags straight from global K.
    f32x4 accqk = {0.f, 0.f, 0.f, 0.f};
    {
      const int key = min(k0 + w * 16 + l15, NSEQ - 1);
      U8 b0, b1;
      b0.u = *(const uint4*)(kbase + (size_t)key * NDH + quad * 8);
      b1.u = *(const uint4*)(kbase + (size_t)key * NDH + 32 + quad * 8);
      accqk = __builtin_amdgcn_mfma_f32_16x16x32_bf16(aq0.v, b0.v, accqk, 0, 0, 0);
      accqk = __builtin_amdgcn_mfma_f32_16x16x32_bf16(aq1.v, b1.v, accqk, 0, 0, 0);
    }
    // T = Q @ posSlice^T (80 rows): wave w -> rsub w; wave 0 also rsub 4.
    const int r0 = k0 - q0 + 524;  // pos row of (q=q0+15, k=k0)
    {
      f32x4 accT = {0.f, 0.f, 0.f, 0.f};
      const int pr = max(0, min(NPOS - 1, r0 + w * 16 + l15));
      U8 b0, b1;
      b0.u = *(const uint4*)(posb + (size_t)pr * NDH + quad * 8);
      b1.u = *(const uint4*)(posb + (size_t)pr * NDH + 32 + quad * 8);
      accT = __builtin_amdgcn_mfma_f32_16x16x32_bf16(aq0.v, b0.v, accT, 0, 0, 0);
      accT = __builtin_amdgcn_mfma_f32_16x16x32_bf16(aq1.v, b1.v, accT, 0, 0, 0);
#pragma unroll
      for (int i = 0; i < 4; i++) Tt[buf][quad * 4 + i][w * 16 + l15] = accT[i];
      if (w == 0) {
        f32x4 accT2 = {0.f, 0.f, 0.f, 0.f};
        const int pr2 = max(0, min(NPOS - 1, r0 + 64 + l15));
        b0.u = *(const uint4*)(posb + (size_t)pr2 * NDH + quad * 8);
        b1.u = *(const uint4*)(posb + (size_t)pr2 * NDH + 32 + quad * 8);
        accT2 = __builtin_amdgcn_mfma_f32_16x16x32_bf16(aq0.v, b0.v, accT2, 0, 0, 0);
        accT2 = __builtin_amdgcn_mfma_f32_16x16x32_bf16(aq1.v, b1.v, accT2, 0, 0, 0);
#pragma unroll
        for (int i = 0; i < 4; i++) Tt[buf][quad * 4 + i][64 + l15] = accT2[i];
      }
    }
    __syncthreads();  // Tt[buf] published (also fences prev-iter gather)
    {
      const int kk = w * 16 + l15;
#pragma unroll
      for (int i = 0; i < 4; i++) {
        const int qq = quad * 4 + i;
        P[qq][k0 + kk] = f2b((accqk[i] + Tt[buf][qq][kk + 15 - qq]) * 0.125f);
      }
    }
  }
  __syncthreads();

  // -------- phase B: masked softmax over k < valid (in-place on bf16 P) ----
  {
    const int r = tid >> 4, c = tid & 15;
    float ml = -1e30f;
    for (int k = c; k < valid; k += 16) ml = fmaxf(ml, b2f16(P[r][k]));
    red[r][c] = ml;
    __syncthreads();
    if (c == 0) {
      float m = red[r][0];
#pragma unroll
      for (int i = 1; i < 16; i++) m = fmaxf(m, red[r][i]);
      red[r][16] = m;
    }
    __syncthreads();
    const float rowmax = red[r][16];
    float sl = 0.f;
    for (int k = c; k < valid; k += 16) {
      const float e = __expf(b2f16(P[r][k]) - rowmax);
      P[r][k] = f2b(e);
      sl += e;
    }
    red[r][c] = sl;
    __syncthreads();
    if (c == 0) {
      float s = 0.f;
#pragma unroll
      for (int i = 0; i < 16; i++) s += red[r][i];
      red[r][16] = 1.f / s;
    }
    __syncthreads();
    const float inv = red[r][16];
    for (int k = c; k < 576; k += 16)
      P[r][k] = (k < valid) ? f2b(b2f16(P[r][k]) * inv) : (unsigned short)0;
  }
  __syncthreads();  // P final

  // -------- phase C: O = P @ V  (A from LDS P, B direct from global vt) ----
  f32x4 acco = {0.f, 0.f, 0.f, 0.f};  // wave w owns dh-subtile w
  const int dh = w * 16 + l15;
  for (int kt = 0; kt < 9; kt++) {
    const int k0 = kt * 64;
#pragma unroll
    for (int c = 0; c < 2; c++) {
      U8 ap, bv;
      ap.u = *(const uint4*)&P[l15][k0 + c * 32 + quad * 8];
      const int kb = min(k0 + c * 32 + quad * 8, NSEQ - 8);  // stay in-row; extra cols have P==0
      bv.u = *(const uint4*)(vbase + (size_t)dh * NSEQ + kb);
      acco = __builtin_amdgcn_mfma_f32_16x16x32_bf16(ap.v, bv.v, acco, 0, 0, 0);
    }
  }
#pragma unroll
  for (int i = 0; i < 4; i++) {
    const int q = q0 + quad * 4 + i;
    if (q < NSEQ) {
      ctx[((size_t)b * NSEQ + q) * ND + h * NDH + dh] = acco[i];
    }
  }
}

// ---------------------------------------------------------------------------
// K3: out projection + bias + residual. (unchanged)
// ---------------------------------------------------------------------------
__global__ __launch_bounds__(256) void out_proj(
    const float* __restrict__ ctx, const float* __restrict__ Wh,
    const float* __restrict__ bh, const float* __restrict__ query,
    float* __restrict__ tmp) {
  __shared__ float AsT[32][68];
  __shared__ float Bs[32][64];
  const int tid = threadIdx.x;
  const int bx = blockIdx.x;
  const int by = blockIdx.y;
  const int m0 = by * 64, n0 = bx * 64;
  const int tx = tid & 15, ty = tid >> 4;
  const int arow = tid >> 2, agrp = tid & 3;
  const int brow = tid >> 3, bgrp = tid & 7;

  float acc[4][4] = {};

  for (int k0 = 0; k0 < 512; k0 += 32) {
    float af[8], bfv[8];
    load8f(ctx + (size_t)(m0 + arow) * 512 + k0 + agrp * 8, af);
    load8f(Wh + (size_t)(k0 + brow) * 512 + n0 + bgrp * 8, bfv);
    __syncthreads();
#pragma unroll
    for (int i = 0; i < 8; i++) AsT[agrp * 8 + i][arow] = af[i];
    *(float4*)&Bs[brow][bgrp * 8] = make_float4(bfv[0], bfv[1], bfv[2], bfv[3]);
    *(float4*)&Bs[brow][bgrp * 8 + 4] = make_float4(bfv[4], bfv[5], bfv[6], bfv[7]);
    __syncthreads();
#pragma unroll
    for (int kk = 0; kk < 32; kk++) {
      const float4 a = *(const float4*)&AsT[kk][ty * 4];
      const float4 b = *(const float4*)&Bs[kk][tx * 4];
      acc[0][0] += a.x * b.x; acc[0][1] += a.x * b.y; acc[0][2] += a.x * b.z; acc[0][3] += a.x * b.w;
      acc[1][0] += a.y * b.x; acc[1][1] += a.y * b.y; acc[1][2] += a.y * b.z; acc[1][3] += a.y * b.w;
      acc[2][0] += a.z * b.x; acc[2][1] += a.z * b.y; acc[2][2] += a.z * b.z; acc[2][3] += a.z * b.w;
      acc[3][0] += a.w * b.x; acc[3][1] += a.w * b.y; acc[3][2] += a.w * b.z; acc[3][3] += a.w * b.w;
    }
  }

#pragma unroll
  for (int i = 0; i < 4; i++) {
    const int m = m0 + ty * 4 + i;
    const size_t off = (size_t)m * 512 + n0 + tx * 4;
    const float4 qv = *(const float4*)&query[off];
    float4 rv;
    rv.x = acc[i][0] + bh[n0 + tx * 4 + 0] + qv.x;
    rv.y = acc[i][1] + bh[n0 + tx * 4 + 1] + qv.y;
    rv.z = acc[i][2] + bh[n0 + tx * 4 + 2] + qv.z;
    rv.w = acc[i][3] + bh[n0 + tx * 4 + 3] + qv.w;
    *(float4*)&tmp[off] = rv;
  }
}

// ---------------------------------------------------------------------------
// K4: layernorm over D=512, eps=1e-7. (unchanged)
// ---------------------------------------------------------------------------
__global__ __launch_bounds__(256) void lnorm(
    const float* __restrict__ tmp, const float* __restrict__ gamma,
    const float* __restrict__ beta, float* __restrict__ out) {
  __shared__ float sred[256];
  const int row = blockIdx.x;
  const int tid = threadIdx.x;
  const size_t base = (size_t)row * 512;
  const float x0 = tmp[base + tid];
  const float x1 = tmp[base + 256 + tid];

  sred[tid] = x0 + x1;
  __syncthreads();
  for (int o = 128; o > 0; o >>= 1) {
    if (tid < o) sred[tid] += sred[tid + o];
    __syncthreads();
  }
  const float mean = sred[0] * (1.f / 512.f);
  __syncthreads();
  const float d0 = x0 - mean, d1 = x1 - mean;
  sred[tid] = d0 * d0 + d1 * d1;
  __syncthreads();
  for (int o = 128; o > 0; o >>= 1) {
    if (tid < o) sred[tid] += sred[tid + o];
    __syncthreads();
  }
  const float var = sred[0] * (1.f / 512.f);
  const float rstd = rsqrtf(var + 1e-7f);
  out[base + tid] = d0 * rstd * gamma[tid] + beta[tid];
  out[base + 256 + tid] = d1 * rstd * gamma[tid + 256] + beta[tid + 256];
}

// ---------------------------------------------------------------------------
// Workspace: qh + kh + vt (bf16, 53.08 MB) + posb (bf16, 138 KB) = 53.2 MB.
// ctx (fp32) lives in d_out; pre-LN tmp (fp32) reuses qh+kh (35.4 MB, dead
// after attn); lnorm writes final fp32 to d_out.
// ---------------------------------------------------------------------------
extern "C" void kernel_launch(void* const* d_in, const int* in_sizes, int n_in,
                              void* d_out, int out_size, void* d_ws, size_t ws_size,
                              hipStream_t stream) {
  const float* query = (const float*)d_in[0];
  const float* Wq = (const float*)d_in[1];
  const float* bq = (const float*)d_in[2];
  const float* Wk = (const float*)d_in[3];
  const float* bk = (const float*)d_in[4];
  const float* Wv = (const float*)d_in[5];
  const float* bv = (const float*)d_in[6];
  const float* Wh = (const float*)d_in[7];
  const float* bh = (const float*)d_in[8];
  const float* pos = (const float*)d_in[9];
  const float* gamma = (const float*)d_in[10];
  const float* beta = (const float*)d_in[11];
  const int* vlen = (const int*)d_in[12];

  bf16* ws = (bf16*)d_ws;
  const size_t QSZ = (size_t)NHB * NSEQ * NDH;  // 8,847,360 elems
  bf16* qh = ws;
  bf16* kh = ws + QSZ;
  bf16* vt = ws + 2 * QSZ;                              // transposed V
  unsigned short* posb = (unsigned short*)(ws + 3 * QSZ);  // bf16 pos
  float* ctx = (float*)d_out;
  float* tmp = (float*)d_ws;
  (void)ws_size;

  pos_cvt<<<dim3(270), 256, 0, stream>>>(pos, posb);
  qkv_proj<<<dim3(8, 270, 3), 256, 0, stream>>>(query, Wq, bq, Wk, bk, Wv, bv, qh, kh, vt);
  attn<<<dim3(34, 256), 256, 0, stream>>>(qh, kh, vt, posb, vlen, ctx);
  out_proj<<<dim3(8, 270), 256, 0, stream>>>(ctx, Wh, bh, query, tmp);
  lnorm<<<NM, 256, 0, stream>>>(tmp, gamma, beta, (float*)d_out);
}

// Round 7
// 442.650 us; speedup vs baseline: 32.5075x; 1.8181x over previous
//
#include <hip/hip_runtime.h>
#include <hip/hip_bf16.h>

typedef __hip_bfloat16 bf16;

// Problem constants
#define NB 32      // batch
#define NSEQ 540   // sequence length
#define ND 512     // model dim
#define NH 8       // heads
#define NDH 64     // head dim
#define NHB 256    // NH*NB
#define NM 17280   // NB*NSEQ
#define NPOS 1079  // 2*539+1

// MFMA types (gfx950 v_mfma_f32_16x16x32_bf16)
typedef __bf16 v8bf __attribute__((ext_vector_type(8)));
typedef float f32x4 __attribute__((ext_vector_type(4)));

union U8 {
  uint4 u;
  unsigned short s[8];
  v8bf v;
};

__device__ __forceinline__ unsigned short f2b(float x) {  // RNE fp32->bf16 bits
  union { float f; unsigned u; } c;
  c.f = x;
  const unsigned r = c.u + 0x7fffu + ((c.u >> 16) & 1u);
  return (unsigned short)(r >> 16);
}

__device__ __forceinline__ float b2f16(unsigned short s) {
  return __uint_as_float(((unsigned)s) << 16);
}

// 16 fp32 (global) -> 16 bf16 -> 32B dst (LDS or global), dst 16B-aligned
__device__ __forceinline__ void cvt16(const float* __restrict__ p,
                                      unsigned short* __restrict__ dst) {
  unsigned short s[16];
#pragma unroll
  for (int i = 0; i < 4; i++) {
    const float4 v = *(const float4*)(p + i * 4);
    s[i * 4 + 0] = f2b(v.x);
    s[i * 4 + 1] = f2b(v.y);
    s[i * 4 + 2] = f2b(v.z);
    s[i * 4 + 3] = f2b(v.w);
  }
  *(uint4*)dst = *(uint4*)s;
  *(uint4*)(dst + 8) = *(uint4*)(s + 8);
}

// ---------------------------------------------------------------------------
// K0a: one-time pos fp32 -> bf16
// ---------------------------------------------------------------------------
__global__ __launch_bounds__(256) void pos_cvt(const float* __restrict__ pos,
                                              unsigned short* __restrict__ posb) {
  const int i = blockIdx.x * 256 + threadIdx.x;
  if (i < NPOS * NDH) posb[i] = f2b(pos[i]);
}

// ---------------------------------------------------------------------------
// K0b: one-time weight cvt+transpose: W[k][n] fp32 -> Wt[n][k] bf16, x4 weights
// ---------------------------------------------------------------------------
__global__ __launch_bounds__(256) void wcvt(
    const float* __restrict__ Wq, const float* __restrict__ Wk,
    const float* __restrict__ Wv, const float* __restrict__ Wh,
    unsigned short* __restrict__ Wt) {
  __shared__ unsigned short T[64][72];
  const int tid = threadIdx.x;
  const int sel = blockIdx.z;
  const float* W = (sel == 0) ? Wq : (sel == 1) ? Wk : (sel == 2) ? Wv : Wh;
  unsigned short* out = Wt + (size_t)sel * ND * ND;
  const int k0 = blockIdx.x * 64, n0 = blockIdx.y * 64;
  const int r = tid >> 2, g = tid & 3;
  // load W[k0+r][n0+g*16 .. +16] -> T[r(k)][g*16(n)..]
  cvt16(W + (size_t)(k0 + r) * ND + n0 + g * 16, &T[r][g * 16]);
  __syncthreads();
  // store out[n0+r][k0+g*16 .. +16] from T[g*16+j][r]
  unsigned short s[16];
#pragma unroll
  for (int j = 0; j < 16; j++) s[j] = T[g * 16 + j][r];
  unsigned short* dst = out + (size_t)(n0 + r) * ND + k0 + g * 16;
  *(uint4*)dst = *(uint4*)s;
  *(uint4*)(dst + 8) = *(uint4*)(s + 8);
}

// ---------------------------------------------------------------------------
// MFMA GEMM core: 128x128 tile, K=512, BK=32, 4 waves (2x2 of 64x64).
// A fp32 [*,512] converted to bf16 in staging; B = Wt bf16 [n][k] rows.
// Frag layouts (m89-verified): A[m=lane&15][k=quad*8+j],
// B[k=quad*8+j][n=lane&15] via row n of Wt, C/D[m=quad*4+reg][n=lane&15].
// LDS pitch 40 ushorts: b128 frag reads conflict-free (2-way max).
// ---------------------------------------------------------------------------
#define GEMM_CORE(APTR)                                                           \
  for (int k0 = 0; k0 < 512; k0 += 32) {                                          \
    __syncthreads();                                                              \
    cvt16(APTR + (size_t)(m0 + srow) * ND + k0 + sh, &As[srow][sh]);              \
    {                                                                             \
      const unsigned short* bp = Bt + (size_t)(n0 + srow) * ND + k0 + sh;         \
      *(uint4*)&Bs[srow][sh] = *(const uint4*)bp;                                 \
      *(uint4*)&Bs[srow][sh + 8] = *(const uint4*)(bp + 8);                       \
    }                                                                             \
    __syncthreads();                                                              \
    U8 af[4], bfr[4];                                                             \
    _Pragma("unroll")                                                             \
    for (int mi = 0; mi < 4; mi++)                                                \
      af[mi].u = *(const uint4*)&As[wr * 64 + mi * 16 + l15][quad * 8];           \
    _Pragma("unroll")                                                             \
    for (int ni = 0; ni < 4; ni++)                                                \
      bfr[ni].u = *(const uint4*)&Bs[wc * 64 + ni * 16 + l15][quad * 8];          \
    _Pragma("unroll")                                                             \
    for (int mi = 0; mi < 4; mi++)                                                \
      _Pragma("unroll")                                                           \
      for (int ni = 0; ni < 4; ni++)                                              \
        acc[mi][ni] = __builtin_amdgcn_mfma_f32_16x16x32_bf16(                    \
            af[mi].v, bfr[ni].v, acc[mi][ni], 0, 0, 0);                           \
  }

// ---------------------------------------------------------------------------
// K1: QKV projection via MFMA. X[17280,512] fp32 @ Wt^T + bias.
// sel 0/1 -> head-major q/k bf16; sel 2 -> transposed vt[x][dh][seq] bf16.
// ---------------------------------------------------------------------------
__global__ __launch_bounds__(256, 2) void qkv_mfma(
    const float* __restrict__ X, const unsigned short* __restrict__ Wt,
    const float* __restrict__ bq, const float* __restrict__ bk,
    const float* __restrict__ bv,
    bf16* __restrict__ qh, bf16* __restrict__ kh, bf16* __restrict__ vt) {
  __shared__ unsigned short As[128][40];
  __shared__ unsigned short Bs[128][40];
  const int tid = threadIdx.x;
  const int sel = blockIdx.z;
  const unsigned short* Bt = Wt + (size_t)sel * ND * ND;
  const float* bias = (sel == 0) ? bq : (sel == 1) ? bk : bv;
  const int m0 = blockIdx.y * 128, n0 = blockIdx.x * 128;
  const int lane = tid & 63, w = tid >> 6;
  const int wr = w & 1, wc = w >> 1;
  const int l15 = lane & 15, quad = lane >> 4;
  const int srow = tid >> 1, sh = (tid & 1) * 16;

  f32x4 acc[4][4];
#pragma unroll
  for (int mi = 0; mi < 4; mi++)
#pragma unroll
    for (int ni = 0; ni < 4; ni++) acc[mi][ni] = (f32x4){0.f, 0.f, 0.f, 0.f};

  GEMM_CORE(X)

  if (sel != 2) {
    unsigned short* o = (unsigned short*)((sel == 0) ? qh : kh);
#pragma unroll
    for (int mi = 0; mi < 4; mi++) {
      const int m = m0 + wr * 64 + mi * 16 + quad * 4;  // mult of 4; 540%4==0
      const int bidx = m / NSEQ;                        // -> rows m..m+3 same batch
      const int seq0 = m - bidx * NSEQ;
#pragma unroll
      for (int ni = 0; ni < 4; ni++) {
        const int n = n0 + wc * 64 + ni * 16 + l15;
        const int h = n >> 6, dh = n & 63;
        const float bsv = bias[n];
        const size_t base = (((size_t)(h * NB + bidx)) * NSEQ + seq0) * NDH + dh;
#pragma unroll
        for (int i = 0; i < 4; i++)
          o[base + (size_t)i * NDH] = f2b(acc[mi][ni][i] + bsv);
      }
    }
  } else {
    unsigned short* o = (unsigned short*)vt;
#pragma unroll
    for (int mi = 0; mi < 4; mi++) {
      const int m = m0 + wr * 64 + mi * 16 + quad * 4;
      const int bidx = m / NSEQ;
      const int seq0 = m - bidx * NSEQ;  // mult of 4 -> uint2 never crosses batch
#pragma unroll
      for (int ni = 0; ni < 4; ni++) {
        const int n = n0 + wc * 64 + ni * 16 + l15;
        const int h = n >> 6, dh = n & 63;
        const float bsv = bias[n];
        unsigned short pk[4];
#pragma unroll
        for (int i = 0; i < 4; i++) pk[i] = f2b(acc[mi][ni][i] + bsv);
        *(uint2*)(o + (((size_t)(h * NB + bidx)) * NDH + dh) * NSEQ + seq0) =
            *(uint2*)pk;
      }
    }
  }
}

// ---------------------------------------------------------------------------
// K3: out projection via MFMA + bias + residual -> tmp fp32.
// ---------------------------------------------------------------------------
__global__ __launch_bounds__(256, 2) void out_mfma(
    const float* __restrict__ ctx, const unsigned short* __restrict__ Wht,
    const float* __restrict__ bh, const float* __restrict__ query,
    float* __restrict__ tmp) {
  __shared__ unsigned short As[128][40];
  __shared__ unsigned short Bs[128][40];
  const int tid = threadIdx.x;
  const unsigned short* Bt = Wht;
  const int m0 = blockIdx.y * 128, n0 = blockIdx.x * 128;
  const int lane = tid & 63, w = tid >> 6;
  const int wr = w & 1, wc = w >> 1;
  const int l15 = lane & 15, quad = lane >> 4;
  const int srow = tid >> 1, sh = (tid & 1) * 16;

  f32x4 acc[4][4];
#pragma unroll
  for (int mi = 0; mi < 4; mi++)
#pragma unroll
    for (int ni = 0; ni < 4; ni++) acc[mi][ni] = (f32x4){0.f, 0.f, 0.f, 0.f};

  GEMM_CORE(ctx)

#pragma unroll
  for (int mi = 0; mi < 4; mi++) {
    const int m = m0 + wr * 64 + mi * 16 + quad * 4;
#pragma unroll
    for (int ni = 0; ni < 4; ni++) {
      const int n = n0 + wc * 64 + ni * 16 + l15;
      const float bsv = bh[n];
#pragma unroll
      for (int i = 0; i < 4; i++) {
        const size_t off = (size_t)(m + i) * ND + n;
        tmp[off] = acc[mi][ni][i] + bsv + query[off];
      }
    }
  }
}

// ---------------------------------------------------------------------------
// K2: attention (unchanged from round 6). Block = (q-tile 16, head-batch x).
// ---------------------------------------------------------------------------
#define PW 584  // P row stride (ushorts)

__global__ __launch_bounds__(256, 4) void attn(
    const bf16* __restrict__ qh, const bf16* __restrict__ kh,
    const bf16* __restrict__ vt, const unsigned short* __restrict__ posb,
    const int* __restrict__ vlen, float* __restrict__ ctx) {
  __shared__ unsigned short P[16][PW];
  __shared__ float Tt[2][16][84];
  __shared__ float red[16][17];

  const int tid = threadIdx.x;
  const int lane = tid & 63;
  const int w = tid >> 6;
  const int l15 = lane & 15;
  const int quad = lane >> 4;
  const int qb = blockIdx.x;
  const int x = blockIdx.y;
  const int b = x & 31, h = x >> 5;
  const int q0 = qb * 16;
  const int valid = vlen[b];
  const bf16* qbase = qh + (size_t)x * NSEQ * NDH;
  const unsigned short* kbase = (const unsigned short*)(kh + (size_t)x * NSEQ * NDH);
  const unsigned short* vbase = (const unsigned short*)(vt + (size_t)x * NDH * NSEQ);

  U8 aq0, aq1;
  {
    const int q = q0 + l15;
    if (q < NSEQ) {
      aq0.u = *(const uint4*)(qbase + (size_t)q * NDH + quad * 8);
      aq1.u = *(const uint4*)(qbase + (size_t)q * NDH + 32 + quad * 8);
    } else {
      aq0.u = make_uint4(0, 0, 0, 0);
      aq1.u = make_uint4(0, 0, 0, 0);
    }
  }

  for (int kt = 0; kt < 9; kt++) {
    const int k0 = kt * 64;
    const int buf = kt & 1;
    f32x4 accqk = {0.f, 0.f, 0.f, 0.f};
    {
      const int key = min(k0 + w * 16 + l15, NSEQ - 1);
      U8 b0, b1;
      b0.u = *(const uint4*)(kbase + (size_t)key * NDH + quad * 8);
      b1.u = *(const uint4*)(kbase + (size_t)key * NDH + 32 + quad * 8);
      accqk = __builtin_amdgcn_mfma_f32_16x16x32_bf16(aq0.v, b0.v, accqk, 0, 0, 0);
      accqk = __builtin_amdgcn_mfma_f32_16x16x32_bf16(aq1.v, b1.v, accqk, 0, 0, 0);
    }
    const int r0 = k0 - q0 + 524;
    {
      f32x4 accT = {0.f, 0.f, 0.f, 0.f};
      const int pr = max(0, min(NPOS - 1, r0 + w * 16 + l15));
      U8 b0, b1;
      b0.u = *(const uint4*)(posb + (size_t)pr * NDH + quad * 8);
      b1.u = *(const uint4*)(posb + (size_t)pr * NDH + 32 + quad * 8);
      accT = __builtin_amdgcn_mfma_f32_16x16x32_bf16(aq0.v, b0.v, accT, 0, 0, 0);
      accT = __builtin_amdgcn_mfma_f32_16x16x32_bf16(aq1.v, b1.v, accT, 0, 0, 0);
#pragma unroll
      for (int i = 0; i < 4; i++) Tt[buf][quad * 4 + i][w * 16 + l15] = accT[i];
      if (w == 0) {
        f32x4 accT2 = {0.f, 0.f, 0.f, 0.f};
        const int pr2 = max(0, min(NPOS - 1, r0 + 64 + l15));
        b0.u = *(const uint4*)(posb + (size_t)pr2 * NDH + quad * 8);
        b1.u = *(const uint4*)(posb + (size_t)pr2 * NDH + 32 + quad * 8);
        accT2 = __builtin_amdgcn_mfma_f32_16x16x32_bf16(aq0.v, b0.v, accT2, 0, 0, 0);
        accT2 = __builtin_amdgcn_mfma_f32_16x16x32_bf16(aq1.v, b1.v, accT2, 0, 0, 0);
#pragma unroll
        for (int i = 0; i < 4; i++) Tt[buf][quad * 4 + i][64 + l15] = accT2[i];
      }
    }
    __syncthreads();
    {
      const int kk = w * 16 + l15;
#pragma unroll
      for (int i = 0; i < 4; i++) {
        const int qq = quad * 4 + i;
        P[qq][k0 + kk] = f2b((accqk[i] + Tt[buf][qq][kk + 15 - qq]) * 0.125f);
      }
    }
  }
  __syncthreads();

  {
    const int r = tid >> 4, c = tid & 15;
    float ml = -1e30f;
    for (int k = c; k < valid; k += 16) ml = fmaxf(ml, b2f16(P[r][k]));
    red[r][c] = ml;
    __syncthreads();
    if (c == 0) {
      float m = red[r][0];
#pragma unroll
      for (int i = 1; i < 16; i++) m = fmaxf(m, red[r][i]);
      red[r][16] = m;
    }
    __syncthreads();
    const float rowmax = red[r][16];
    float sl = 0.f;
    for (int k = c; k < valid; k += 16) {
      const float e = __expf(b2f16(P[r][k]) - rowmax);
      P[r][k] = f2b(e);
      sl += e;
    }
    red[r][c] = sl;
    __syncthreads();
    if (c == 0) {
      float s = 0.f;
#pragma unroll
      for (int i = 0; i < 16; i++) s += red[r][i];
      red[r][16] = 1.f / s;
    }
    __syncthreads();
    const float inv = red[r][16];
    for (int k = c; k < 576; k += 16)
      P[r][k] = (k < valid) ? f2b(b2f16(P[r][k]) * inv) : (unsigned short)0;
  }
  __syncthreads();

  f32x4 acco = {0.f, 0.f, 0.f, 0.f};
  const int dh = w * 16 + l15;
  for (int kt = 0; kt < 9; kt++) {
    const int k0 = kt * 64;
#pragma unroll
    for (int c = 0; c < 2; c++) {
      U8 ap, bv;
      ap.u = *(const uint4*)&P[l15][k0 + c * 32 + quad * 8];
      const int kb = min(k0 + c * 32 + quad * 8, NSEQ - 8);
      bv.u = *(const uint4*)(vbase + (size_t)dh * NSEQ + kb);
      acco = __builtin_amdgcn_mfma_f32_16x16x32_bf16(ap.v, bv.v, acco, 0, 0, 0);
    }
  }
#pragma unroll
  for (int i = 0; i < 4; i++) {
    const int q = q0 + quad * 4 + i;
    if (q < NSEQ) {
      ctx[((size_t)b * NSEQ + q) * ND + h * NDH + dh] = acco[i];
    }
  }
}

// ---------------------------------------------------------------------------
// K4: layernorm over D=512, eps=1e-7. (unchanged)
// ---------------------------------------------------------------------------
__global__ __launch_bounds__(256) void lnorm(
    const float* __restrict__ tmp, const float* __restrict__ gamma,
    const float* __restrict__ beta, float* __restrict__ out) {
  __shared__ float sred[256];
  const int row = blockIdx.x;
  const int tid = threadIdx.x;
  const size_t base = (size_t)row * 512;
  const float x0 = tmp[base + tid];
  const float x1 = tmp[base + 256 + tid];

  sred[tid] = x0 + x1;
  __syncthreads();
  for (int o = 128; o > 0; o >>= 1) {
    if (tid < o) sred[tid] += sred[tid + o];
    __syncthreads();
  }
  const float mean = sred[0] * (1.f / 512.f);
  __syncthreads();
  const float d0 = x0 - mean, d1 = x1 - mean;
  sred[tid] = d0 * d0 + d1 * d1;
  __syncthreads();
  for (int o = 128; o > 0; o >>= 1) {
    if (tid < o) sred[tid] += sred[tid + o];
    __syncthreads();
  }
  const float var = sred[0] * (1.f / 512.f);
  const float rstd = rsqrtf(var + 1e-7f);
  out[base + tid] = d0 * rstd * gamma[tid] + beta[tid];
  out[base + 256 + tid] = d1 * rstd * gamma[tid + 256] + beta[tid + 256];
}

// ---------------------------------------------------------------------------
// Workspace: qh + kh + vt (bf16, 53.08 MB) + posb (138 KB) + Wt (bf16, 2 MB)
// = 55.3 MB. ctx (fp32) lives in d_out; pre-LN tmp (fp32) reuses qh+kh (dead
// after attn); lnorm writes final fp32 to d_out.
// ---------------------------------------------------------------------------
extern "C" void kernel_launch(void* const* d_in, const int* in_sizes, int n_in,
                              void* d_out, int out_size, void* d_ws, size_t ws_size,
                              hipStream_t stream) {
  const float* query = (const float*)d_in[0];
  const float* Wq = (const float*)d_in[1];
  const float* bq = (const float*)d_in[2];
  const float* Wk = (const float*)d_in[3];
  const float* bk = (const float*)d_in[4];
  const float* Wv = (const float*)d_in[5];
  const float* bv = (const float*)d_in[6];
  const float* Wh = (const float*)d_in[7];
  const float* bh = (const float*)d_in[8];
  const float* pos = (const float*)d_in[9];
  const float* gamma = (const float*)d_in[10];
  const float* beta = (const float*)d_in[11];
  const int* vlen = (const int*)d_in[12];

  bf16* ws = (bf16*)d_ws;
  const size_t QSZ = (size_t)NHB * NSEQ * NDH;  // 8,847,360 elems
  bf16* qh = ws;
  bf16* kh = ws + QSZ;
  bf16* vt = ws + 2 * QSZ;
  unsigned short* posb = (unsigned short*)(ws + 3 * QSZ);
  unsigned short* Wtb = posb + (size_t)NPOS * NDH;  // 4 x [512][512] bf16
  float* ctx = (float*)d_out;
  float* tmp = (float*)d_ws;
  (void)ws_size;

  pos_cvt<<<dim3(270), 256, 0, stream>>>(pos, posb);
  wcvt<<<dim3(8, 8, 4), 256, 0, stream>>>(Wq, Wk, Wv, Wh, Wtb);
  qkv_mfma<<<dim3(4, 135, 3), 256, 0, stream>>>(query, Wtb, bq, bk, bv, qh, kh, vt);
  attn<<<dim3(34, 256), 256, 0, stream>>>(qh, kh, vt, posb, vlen, ctx);
  out_mfma<<<dim3(4, 135), 256, 0, stream>>>(ctx, Wtb + 3 * (size_t)ND * ND, bh, query, tmp);
  lnorm<<<NM, 256, 0, stream>>>(tmp, gamma, beta, (float*)d_out);
}

// Round 8
// 423.821 us; speedup vs baseline: 33.9516x; 1.0444x over previous
//
#include <hip/hip_runtime.h>
#include <hip/hip_bf16.h>

typedef __hip_bfloat16 bf16;

// Problem constants
#define NB 32      // batch
#define NSEQ 540   // sequence length
#define ND 512     // model dim
#define NH 8       // heads
#define NDH 64     // head dim
#define NHB 256    // NH*NB
#define NM 17280   // NB*NSEQ
#define NPOS 1079  // 2*539+1
#define VTP 544    // vt row pitch (16B-aligned rows for all dh)

// MFMA types (gfx950 v_mfma_f32_16x16x32_bf16)
typedef __bf16 v8bf __attribute__((ext_vector_type(8)));
typedef float f32x4 __attribute__((ext_vector_type(4)));

union U8 {
  uint4 u;
  unsigned short s[8];
  v8bf v;
};

__device__ __forceinline__ unsigned short f2b(float x) {  // RNE fp32->bf16 bits
  union { float f; unsigned u; } c;
  c.f = x;
  const unsigned r = c.u + 0x7fffu + ((c.u >> 16) & 1u);
  return (unsigned short)(r >> 16);
}

__device__ __forceinline__ float b2f16(unsigned short s) {
  return __uint_as_float(((unsigned)s) << 16);
}

// 16 fp32 (global) -> 16 bf16 -> 32B dst (LDS or global), dst 16B-aligned
__device__ __forceinline__ void cvt16(const float* __restrict__ p,
                                      unsigned short* __restrict__ dst) {
  unsigned short s[16];
#pragma unroll
  for (int i = 0; i < 4; i++) {
    const float4 v = *(const float4*)(p + i * 4);
    s[i * 4 + 0] = f2b(v.x);
    s[i * 4 + 1] = f2b(v.y);
    s[i * 4 + 2] = f2b(v.z);
    s[i * 4 + 3] = f2b(v.w);
  }
  *(uint4*)dst = *(uint4*)s;
  *(uint4*)(dst + 8) = *(uint4*)(s + 8);
}

// ---------------------------------------------------------------------------
// K0a: one-time pos fp32 -> bf16
// ---------------------------------------------------------------------------
__global__ __launch_bounds__(256) void pos_cvt(const float* __restrict__ pos,
                                              unsigned short* __restrict__ posb) {
  const int i = blockIdx.x * 256 + threadIdx.x;
  if (i < NPOS * NDH) posb[i] = f2b(pos[i]);
}

// ---------------------------------------------------------------------------
// K0b: one-time weight cvt+transpose: W[k][n] fp32 -> Wt[n][k] bf16, x4 weights
// ---------------------------------------------------------------------------
__global__ __launch_bounds__(256) void wcvt(
    const float* __restrict__ Wq, const float* __restrict__ Wk,
    const float* __restrict__ Wv, const float* __restrict__ Wh,
    unsigned short* __restrict__ Wt) {
  __shared__ unsigned short T[64][72];
  const int tid = threadIdx.x;
  const int sel = blockIdx.z;
  const float* W = (sel == 0) ? Wq : (sel == 1) ? Wk : (sel == 2) ? Wv : Wh;
  unsigned short* out = Wt + (size_t)sel * ND * ND;
  const int k0 = blockIdx.x * 64, n0 = blockIdx.y * 64;
  const int r = tid >> 2, g = tid & 3;
  cvt16(W + (size_t)(k0 + r) * ND + n0 + g * 16, &T[r][g * 16]);
  __syncthreads();
  unsigned short s[16];
#pragma unroll
  for (int j = 0; j < 16; j++) s[j] = T[g * 16 + j][r];
  unsigned short* dst = out + (size_t)(n0 + r) * ND + k0 + g * 16;
  *(uint4*)dst = *(uint4*)s;
  *(uint4*)(dst + 8) = *(uint4*)(s + 8);
}

// ---------------------------------------------------------------------------
// MFMA GEMM core: 128x128 tile, K=512, BK=32, 4 waves (2x2 of 64x64).
// ---------------------------------------------------------------------------
#define GEMM_CORE(APTR)                                                           \
  for (int k0 = 0; k0 < 512; k0 += 32) {                                          \
    __syncthreads();                                                              \
    cvt16(APTR + (size_t)(m0 + srow) * ND + k0 + sh, &As[srow][sh]);              \
    {                                                                             \
      const unsigned short* bp = Bt + (size_t)(n0 + srow) * ND + k0 + sh;         \
      *(uint4*)&Bs[srow][sh] = *(const uint4*)bp;                                 \
      *(uint4*)&Bs[srow][sh + 8] = *(const uint4*)(bp + 8);                       \
    }                                                                             \
    __syncthreads();                                                              \
    U8 af[4], bfr[4];                                                             \
    _Pragma("unroll")                                                             \
    for (int mi = 0; mi < 4; mi++)                                                \
      af[mi].u = *(const uint4*)&As[wr * 64 + mi * 16 + l15][quad * 8];           \
    _Pragma("unroll")                                                             \
    for (int ni = 0; ni < 4; ni++)                                                \
      bfr[ni].u = *(const uint4*)&Bs[wc * 64 + ni * 16 + l15][quad * 8];          \
    _Pragma("unroll")                                                             \
    for (int mi = 0; mi < 4; mi++)                                                \
      _Pragma("unroll")                                                           \
      for (int ni = 0; ni < 4; ni++)                                              \
        acc[mi][ni] = __builtin_amdgcn_mfma_f32_16x16x32_bf16(                    \
            af[mi].v, bfr[ni].v, acc[mi][ni], 0, 0, 0);                           \
  }

// ---------------------------------------------------------------------------
// K1: QKV projection via MFMA. X[17280,512] fp32 @ Wt^T + bias.
// sel 0/1 -> head-major q/k bf16; sel 2 -> transposed vt[x][dh][VTP] bf16.
// ---------------------------------------------------------------------------
__global__ __launch_bounds__(256, 2) void qkv_mfma(
    const float* __restrict__ X, const unsigned short* __restrict__ Wt,
    const float* __restrict__ bq, const float* __restrict__ bk,
    const float* __restrict__ bv,
    bf16* __restrict__ qh, bf16* __restrict__ kh, bf16* __restrict__ vt) {
  __shared__ unsigned short As[128][40];
  __shared__ unsigned short Bs[128][40];
  const int tid = threadIdx.x;
  const int sel = blockIdx.z;
  const unsigned short* Bt = Wt + (size_t)sel * ND * ND;
  const float* bias = (sel == 0) ? bq : (sel == 1) ? bk : bv;
  const int m0 = blockIdx.y * 128, n0 = blockIdx.x * 128;
  const int lane = tid & 63, w = tid >> 6;
  const int wr = w & 1, wc = w >> 1;
  const int l15 = lane & 15, quad = lane >> 4;
  const int srow = tid >> 1, sh = (tid & 1) * 16;

  f32x4 acc[4][4];
#pragma unroll
  for (int mi = 0; mi < 4; mi++)
#pragma unroll
    for (int ni = 0; ni < 4; ni++) acc[mi][ni] = (f32x4){0.f, 0.f, 0.f, 0.f};

  GEMM_CORE(X)

  if (sel != 2) {
    unsigned short* o = (unsigned short*)((sel == 0) ? qh : kh);
#pragma unroll
    for (int mi = 0; mi < 4; mi++) {
      const int m = m0 + wr * 64 + mi * 16 + quad * 4;  // mult of 4; 540%4==0
      const int bidx = m / NSEQ;
      const int seq0 = m - bidx * NSEQ;
#pragma unroll
      for (int ni = 0; ni < 4; ni++) {
        const int n = n0 + wc * 64 + ni * 16 + l15;
        const int h = n >> 6, dh = n & 63;
        const float bsv = bias[n];
        const size_t base = (((size_t)(h * NB + bidx)) * NSEQ + seq0) * NDH + dh;
#pragma unroll
        for (int i = 0; i < 4; i++)
          o[base + (size_t)i * NDH] = f2b(acc[mi][ni][i] + bsv);
      }
    }
  } else {
    unsigned short* o = (unsigned short*)vt;
#pragma unroll
    for (int mi = 0; mi < 4; mi++) {
      const int m = m0 + wr * 64 + mi * 16 + quad * 4;
      const int bidx = m / NSEQ;
      const int seq0 = m - bidx * NSEQ;  // mult of 4 -> uint2 never crosses batch
#pragma unroll
      for (int ni = 0; ni < 4; ni++) {
        const int n = n0 + wc * 64 + ni * 16 + l15;
        const int h = n >> 6, dh = n & 63;
        const float bsv = bias[n];
        unsigned short pk[4];
#pragma unroll
        for (int i = 0; i < 4; i++) pk[i] = f2b(acc[mi][ni][i] + bsv);
        *(uint2*)(o + (((size_t)(h * NB + bidx)) * NDH + dh) * VTP + seq0) =
            *(uint2*)pk;
      }
    }
  }
}

// ---------------------------------------------------------------------------
// K3: out projection via MFMA + bias + residual -> tmp fp32.
// ---------------------------------------------------------------------------
__global__ __launch_bounds__(256, 2) void out_mfma(
    const float* __restrict__ ctx, const unsigned short* __restrict__ Wht,
    const float* __restrict__ bh, const float* __restrict__ query,
    float* __restrict__ tmp) {
  __shared__ unsigned short As[128][40];
  __shared__ unsigned short Bs[128][40];
  const int tid = threadIdx.x;
  const unsigned short* Bt = Wht;
  const int m0 = blockIdx.y * 128, n0 = blockIdx.x * 128;
  const int lane = tid & 63, w = tid >> 6;
  const int wr = w & 1, wc = w >> 1;
  const int l15 = lane & 15, quad = lane >> 4;
  const int srow = tid >> 1, sh = (tid & 1) * 16;

  f32x4 acc[4][4];
#pragma unroll
  for (int mi = 0; mi < 4; mi++)
#pragma unroll
    for (int ni = 0; ni < 4; ni++) acc[mi][ni] = (f32x4){0.f, 0.f, 0.f, 0.f};

  GEMM_CORE(ctx)

#pragma unroll
  for (int mi = 0; mi < 4; mi++) {
    const int m = m0 + wr * 64 + mi * 16 + quad * 4;
#pragma unroll
    for (int ni = 0; ni < 4; ni++) {
      const int n = n0 + wc * 64 + ni * 16 + l15;
      const float bsv = bh[n];
#pragma unroll
      for (int i = 0; i < 4; i++) {
        const size_t off = (size_t)(m + i) * ND + n;
        tmp[off] = acc[mi][ni][i] + bsv + query[off];
      }
    }
  }
}

// ---------------------------------------------------------------------------
// K2: attention v4: software-pipelined. Block = (q-tile 16, head-batch x).
// Phase A: 1-deep prefetch of K/pos B-frags across the per-tile barrier;
// index clamps removed (OOB rows only feed P cols >= 540 / q >= NSEQ, which
// are zeroed or discarded; strays stay inside ws). Softmax: normalization
// folded into PV epilogue (O *= 1/l); pad cols zero-filled once.
// Phase C: V prefetched (first frag issued before softmax); vt pitch 544
// keeps all loads 16B-aligned.
// ---------------------------------------------------------------------------
#define PW 584  // P row stride (ushorts)

__global__ __launch_bounds__(256, 4) void attn(
    const bf16* __restrict__ qh, const bf16* __restrict__ kh,
    const bf16* __restrict__ vt, const unsigned short* __restrict__ posb,
    const int* __restrict__ vlen, float* __restrict__ ctx) {
  __shared__ unsigned short P[16][PW];  // 18.7 KB
  __shared__ float Tt[2][16][84];       // 10.8 KB
  __shared__ float red[16][17];         //  1.1 KB

  const int tid = threadIdx.x;
  const int lane = tid & 63;
  const int w = tid >> 6;
  const int l15 = lane & 15;
  const int quad = lane >> 4;
  const int qb = blockIdx.x;
  const int x = blockIdx.y;
  const int b = x & 31, h = x >> 5;
  const int q0 = qb * 16;
  const int valid = vlen[b];
  const bf16* qbase = qh + (size_t)x * NSEQ * NDH;
  const unsigned short* kbase = (const unsigned short*)(kh + (size_t)x * NSEQ * NDH);
  const unsigned short* vbase = (const unsigned short*)(vt + (size_t)x * NDH * VTP);

  // Q A-fragments, zero-filled rows past NSEQ
  U8 aq0, aq1;
  {
    const int q = q0 + l15;
    if (q < NSEQ) {
      aq0.u = *(const uint4*)(qbase + (size_t)q * NDH + quad * 8);
      aq1.u = *(const uint4*)(qbase + (size_t)q * NDH + 32 + quad * 8);
    } else {
      aq0.u = make_uint4(0, 0, 0, 0);
      aq1.u = make_uint4(0, 0, 0, 0);
    }
  }

  // -------- phase A: scores, 1-deep prefetch --------
  U8 ck0, ck1, cp0, cp1, ce0, ce1;
  {
    const int key = w * 16 + l15;  // kt = 0
    ck0.u = *(const uint4*)(kbase + (size_t)key * NDH + quad * 8);
    ck1.u = *(const uint4*)(kbase + (size_t)key * NDH + 32 + quad * 8);
    const long pr = (long)(524 - q0 + w * 16 + l15);  // may be slightly <0: stays in ws
    cp0.u = *(const uint4*)(posb + pr * NDH + quad * 8);
    cp1.u = *(const uint4*)(posb + pr * NDH + 32 + quad * 8);
    if (w == 0) {
      const long pr2 = (long)(524 - q0 + 64 + l15);
      ce0.u = *(const uint4*)(posb + pr2 * NDH + quad * 8);
      ce1.u = *(const uint4*)(posb + pr2 * NDH + 32 + quad * 8);
    }
  }

  for (int kt = 0; kt < 9; kt++) {
    const int buf = kt & 1;
    U8 nk0, nk1, np0, np1, ne0, ne1;
    if (kt < 8) {  // issue next tile's loads before computing current
      const int k1 = kt * 64 + 64;
      const int key = k1 + w * 16 + l15;
      nk0.u = *(const uint4*)(kbase + (size_t)key * NDH + quad * 8);
      nk1.u = *(const uint4*)(kbase + (size_t)key * NDH + 32 + quad * 8);
      const long pr = (long)(k1 - q0 + 524 + w * 16 + l15);
      np0.u = *(const uint4*)(posb + pr * NDH + quad * 8);
      np1.u = *(const uint4*)(posb + pr * NDH + 32 + quad * 8);
      if (w == 0) {
        const long pr2 = (long)(k1 - q0 + 524 + 64 + l15);
        ne0.u = *(const uint4*)(posb + pr2 * NDH + quad * 8);
        ne1.u = *(const uint4*)(posb + pr2 * NDH + 32 + quad * 8);
      }
    }

    f32x4 accqk = {0.f, 0.f, 0.f, 0.f};
    accqk = __builtin_amdgcn_mfma_f32_16x16x32_bf16(aq0.v, ck0.v, accqk, 0, 0, 0);
    accqk = __builtin_amdgcn_mfma_f32_16x16x32_bf16(aq1.v, ck1.v, accqk, 0, 0, 0);
    {
      f32x4 accT = {0.f, 0.f, 0.f, 0.f};
      accT = __builtin_amdgcn_mfma_f32_16x16x32_bf16(aq0.v, cp0.v, accT, 0, 0, 0);
      accT = __builtin_amdgcn_mfma_f32_16x16x32_bf16(aq1.v, cp1.v, accT, 0, 0, 0);
#pragma unroll
      for (int i = 0; i < 4; i++) Tt[buf][quad * 4 + i][w * 16 + l15] = accT[i];
      if (w == 0) {
        f32x4 accT2 = {0.f, 0.f, 0.f, 0.f};
        accT2 = __builtin_amdgcn_mfma_f32_16x16x32_bf16(aq0.v, ce0.v, accT2, 0, 0, 0);
        accT2 = __builtin_amdgcn_mfma_f32_16x16x32_bf16(aq1.v, ce1.v, accT2, 0, 0, 0);
#pragma unroll
        for (int i = 0; i < 4; i++) Tt[buf][quad * 4 + i][64 + l15] = accT2[i];
      }
    }
    __syncthreads();  // Tt[buf] published
    {
      const int k0 = kt * 64;
      const int kk = w * 16 + l15;
#pragma unroll
      for (int i = 0; i < 4; i++) {
        const int qq = quad * 4 + i;
        P[qq][k0 + kk] = f2b((accqk[i] + Tt[buf][qq][kk + 15 - qq]) * 0.125f);
      }
    }
    ck0 = nk0; ck1 = nk1; cp0 = np0; cp1 = np1;
    if (w == 0) { ce0 = ne0; ce1 = ne1; }
  }

  // issue first V fragment now; it drains during softmax
  const int dh = w * 16 + l15;
  const unsigned short* vrow = vbase + (size_t)dh * VTP;
  U8 cv;
  cv.u = *(const uint4*)(vrow + quad * 8);

  __syncthreads();  // P complete

  // -------- phase B: masked softmax (normalization deferred to epilogue) ---
  {
    const int r = tid >> 4, c = tid & 15;
    float ml = -1e30f;
    for (int k = c; k < valid; k += 16) ml = fmaxf(ml, b2f16(P[r][k]));
    red[r][c] = ml;
    __syncthreads();
    if (c == 0) {
      float m = red[r][0];
#pragma unroll
      for (int i = 1; i < 16; i++) m = fmaxf(m, red[r][i]);
      red[r][16] = m;
    }
    __syncthreads();
    const float rowmax = red[r][16];
    float sl = 0.f;
    for (int k = c; k < valid; k += 16) {
      const float e = __expf(b2f16(P[r][k]) - rowmax);
      P[r][k] = f2b(e);
      sl += e;
    }
    for (int k = valid + c; k < 576; k += 16) P[r][k] = 0;  // pad + masked cols
    red[r][c] = sl;
    __syncthreads();
    if (c == 0) {
      float s = 0.f;
#pragma unroll
      for (int i = 0; i < 16; i++) s += red[r][i];
      red[r][16] = 1.f / s;
    }
    __syncthreads();
  }

  // -------- phase C: O = (P_unnorm @ V) * inv, V prefetched --------
  f32x4 acco = {0.f, 0.f, 0.f, 0.f};
  for (int ci = 0; ci < 18; ci++) {
    U8 nv;
    if (ci < 17) nv.u = *(const uint4*)(vrow + (ci + 1) * 32 + quad * 8);
    U8 ap;
    ap.u = *(const uint4*)&P[l15][ci * 32 + quad * 8];
    acco = __builtin_amdgcn_mfma_f32_16x16x32_bf16(ap.v, cv.v, acco, 0, 0, 0);
    cv = nv;
  }
#pragma unroll
  for (int i = 0; i < 4; i++) {
    const int q = q0 + quad * 4 + i;
    if (q < NSEQ) {
      ctx[((size_t)b * NSEQ + q) * ND + h * NDH + dh] = acco[i] * red[quad * 4 + i][16];
    }
  }
}

// ---------------------------------------------------------------------------
// K4: layernorm over D=512, eps=1e-7. (unchanged)
// ---------------------------------------------------------------------------
__global__ __launch_bounds__(256) void lnorm(
    const float* __restrict__ tmp, const float* __restrict__ gamma,
    const float* __restrict__ beta, float* __restrict__ out) {
  __shared__ float sred[256];
  const int row = blockIdx.x;
  const int tid = threadIdx.x;
  const size_t base = (size_t)row * 512;
  const float x0 = tmp[base + tid];
  const float x1 = tmp[base + 256 + tid];

  sred[tid] = x0 + x1;
  __syncthreads();
  for (int o = 128; o > 0; o >>= 1) {
    if (tid < o) sred[tid] += sred[tid + o];
    __syncthreads();
  }
  const float mean = sred[0] * (1.f / 512.f);
  __syncthreads();
  const float d0 = x0 - mean, d1 = x1 - mean;
  sred[tid] = d0 * d0 + d1 * d1;
  __syncthreads();
  for (int o = 128; o > 0; o >>= 1) {
    if (tid < o) sred[tid] += sred[tid + o];
    __syncthreads();
  }
  const float var = sred[0] * (1.f / 512.f);
  const float rstd = rsqrtf(var + 1e-7f);
  out[base + tid] = d0 * rstd * gamma[tid] + beta[tid];
  out[base + 256 + tid] = d1 * rstd * gamma[tid + 256] + beta[tid + 256];
}

// ---------------------------------------------------------------------------
// Workspace: qh + kh (35.4 MB) + vt (17.8 MB, pitch 544) + posb (138 KB)
// + Wt (2 MB) = 55.4 MB. ctx (fp32) lives in d_out; pre-LN tmp (fp32) reuses
// qh+kh (dead after attn); lnorm writes final fp32 to d_out.
// ---------------------------------------------------------------------------
extern "C" void kernel_launch(void* const* d_in, const int* in_sizes, int n_in,
                              void* d_out, int out_size, void* d_ws, size_t ws_size,
                              hipStream_t stream) {
  const float* query = (const float*)d_in[0];
  const float* Wq = (const float*)d_in[1];
  const float* bq = (const float*)d_in[2];
  const float* Wk = (const float*)d_in[3];
  const float* bk = (const float*)d_in[4];
  const float* Wv = (const float*)d_in[5];
  const float* bv = (const float*)d_in[6];
  const float* Wh = (const float*)d_in[7];
  const float* bh = (const float*)d_in[8];
  const float* pos = (const float*)d_in[9];
  const float* gamma = (const float*)d_in[10];
  const float* beta = (const float*)d_in[11];
  const int* vlen = (const int*)d_in[12];

  bf16* ws = (bf16*)d_ws;
  const size_t QSZ = (size_t)NHB * NSEQ * NDH;   // 8,847,360 elems
  const size_t VSZ = (size_t)NHB * NDH * VTP;    // 8,912,896 elems
  bf16* qh = ws;
  bf16* kh = ws + QSZ;
  bf16* vt = ws + 2 * QSZ;
  unsigned short* posb = (unsigned short*)(ws + 2 * QSZ + VSZ);
  unsigned short* Wtb = posb + (size_t)NPOS * NDH;  // 4 x [512][512] bf16
  float* ctx = (float*)d_out;
  float* tmp = (float*)d_ws;  // reuses qh+kh (35.4 MB)
  (void)ws_size;

  pos_cvt<<<dim3(270), 256, 0, stream>>>(pos, posb);
  wcvt<<<dim3(8, 8, 4), 256, 0, stream>>>(Wq, Wk, Wv, Wh, Wtb);
  qkv_mfma<<<dim3(4, 135, 3), 256, 0, stream>>>(query, Wtb, bq, bk, bv, qh, kh, vt);
  attn<<<dim3(34, 256), 256, 0, stream>>>(qh, kh, vt, posb, vlen, ctx);
  out_mfma<<<dim3(4, 135), 256, 0, stream>>>(ctx, Wtb + 3 * (size_t)ND * ND, bh, query, tmp);
  lnorm<<<NM, 256, 0, stream>>>(tmp, gamma, beta, (float*)d_out);
}